// Round 17
// baseline (233.447 us; speedup 1.0000x reference)
//
#include <hip/hip_runtime.h>
#include <hip/hip_bf16.h>
#include <math.h>

// B=2, SX=SY=2048, XD=YD=1024, P=64, H=16, MULT=4
typedef __bf16 bf16_t;
typedef __bf16 bf16x8 __attribute__((ext_vector_type(8)));
typedef __bf16 bf16x4 __attribute__((ext_vector_type(4)));
typedef float f32x4 __attribute__((ext_vector_type(4)));

#define QSCALE 0.18033688011112042f /* 0.125 * log2(e): scores in log2 units */

static __device__ __forceinline__ f32x4 mfma16(bf16x8 a, bf16x8 b, f32x4 c) {
  return __builtin_amdgcn_mfma_f32_16x16x32_bf16(a, b, c, 0, 0, 0);
}

static __device__ __forceinline__ float exp2_fast(float x) {
  float r;
  asm("v_exp_f32 %0, %1" : "=v"(r) : "v"(x));
  return r;
}

// tanh-form GELU: 0.5x(1+tanh(u)) = x*e/(e+1), e = exp(2u), u = c1*x + c2*x^3.
static __device__ __forceinline__ float gelu_f(float x) {
  const float u = x * (0.7978845608028654f + 0.03567740813636141f * x * x);
  const float a = fminf(u * 2.885390081777927f, 126.0f);
  const float e = exp2_fast(a);
  float r;
  asm("v_rcp_f32 %0, %1" : "=v"(r) : "v"(e + 1.0f));
  return x * e * r;
}

typedef __attribute__((address_space(1))) const void as1_void;
typedef __attribute__((address_space(3))) void as3_void;
static __device__ __forceinline__ void gload16(const void* g, void* s) {
  __builtin_amdgcn_global_load_lds((as1_void*)g, (as3_void*)s, 16, 0, 0);
}

// head-major index: [b][h][s][p] from (row = b*2048+s, col = h*64+p)
static __device__ __forceinline__ long hmi(int row, int col) {
  return ((((long)(row >> 11) * 16 + (col >> 6)) * 2048) + (row & 2047)) * 64 + (col & 63);
}

// -------- merged prep: 6 weight transposes + both input LayerNorms, one launch --------
__global__ __launch_bounds__(256) void prep_all(
    const float* __restrict__ Wq, const float* __restrict__ Wk, const float* __restrict__ Wv,
    const float* __restrict__ Wo, const float* __restrict__ W1, const float* __restrict__ W2,
    bf16_t* __restrict__ WqkvT, bf16_t* __restrict__ WoT, bf16_t* __restrict__ W1T,
    bf16_t* __restrict__ W2T, const float* __restrict__ x, const float* __restrict__ y,
    const float* __restrict__ gx, const float* __restrict__ bex, const float* __restrict__ gy,
    const float* __restrict__ bey, bf16_t* __restrict__ xn, bf16_t* __restrict__ yn) {
  const int bid = blockIdx.x;
  if (bid >= 3072) {
    const int lrow = bid - 3072;
    const float* in = lrow < 4096 ? x : y;
    const float* g = lrow < 4096 ? gx : gy;
    const float* be = lrow < 4096 ? bex : bey;
    bf16_t* out = lrow < 4096 ? xn : yn;
    const int row = lrow & 4095;
    const int t = threadIdx.x;
    const float4 xv = ((const float4*)(in + (long)row * 1024))[t];
    float s1 = xv.x + xv.y + xv.z + xv.w;
    float s2 = xv.x * xv.x + xv.y * xv.y + xv.z * xv.z + xv.w * xv.w;
#pragma unroll
    for (int m = 1; m < 64; m <<= 1) {
      s1 += __shfl_xor(s1, m);
      s2 += __shfl_xor(s2, m);
    }
    __shared__ float r1[4], r2[4];
    if ((t & 63) == 0) { r1[t >> 6] = s1; r2[t >> 6] = s2; }
    __syncthreads();
    s1 = r1[0] + r1[1] + r1[2] + r1[3];
    s2 = r2[0] + r2[1] + r2[2] + r2[3];
    const float mean = s1 * (1.0f / 1024.0f);
    float var = s2 * (1.0f / 1024.0f) - mean * mean;
    const float rstd = rsqrtf(fmaxf(var, 0.0f) + 1e-5f);
    const float4 gv = ((const float4*)g)[t];
    const float4 bv = ((const float4*)be)[t];
    bf16x4 o;
    o[0] = (bf16_t)((xv.x - mean) * rstd * gv.x + bv.x);
    o[1] = (bf16_t)((xv.y - mean) * rstd * gv.y + bv.y);
    o[2] = (bf16_t)((xv.z - mean) * rstd * gv.z + bv.z);
    o[3] = (bf16_t)((xv.w - mean) * rstd * gv.w + bv.w);
    *(bf16x4*)(out + (long)row * 1024 + t * 4) = o;
    return;
  }
  const float* inp;
  bf16_t* outp;
  int istride, ostride, i0, j0;
  if (bid < 768) {
    const int wsel = bid >> 8, rem = bid & 255;
    const int h = rem >> 4, xt = rem & 15;
    const float* W = wsel == 0 ? Wq : (wsel == 1 ? Wk : Wv);
    inp = W + h * 65536;
    outp = WqkvT + (long)wsel * 1048576 + h * 65536;
    istride = 64; ostride = 1024; i0 = xt * 64; j0 = 0;
  } else if (bid < 1024) {
    const int rem = bid - 768;
    inp = Wo; outp = WoT; istride = 1024; ostride = 1024;
    i0 = (rem & 15) * 64; j0 = (rem >> 4) * 64;
  } else if (bid < 2048) {
    const int rem = bid - 1024;
    inp = W1; outp = W1T; istride = 4096; ostride = 1024;
    i0 = (rem & 15) * 64; j0 = (rem >> 4) * 64;
  } else {
    const int rem = bid - 2048;
    inp = W2; outp = W2T; istride = 1024; ostride = 4096;
    i0 = (rem >> 4) * 64; j0 = (rem & 15) * 64;
  }
  __shared__ bf16_t tile[64][65];
  const int r = threadIdx.x >> 2, cs = (threadIdx.x & 3) * 16;
#pragma unroll
  for (int jj = 0; jj < 16; jj++)
    tile[cs + jj][r] = (bf16_t)inp[(long)(i0 + r) * istride + j0 + cs + jj];
  __syncthreads();
#pragma unroll
  for (int jj = 0; jj < 16; jj++)
    outp[(long)(j0 + r) * ostride + i0 + cs + jj] = tile[r][cs + jj];
}

// ---------------- LayerNorm (standalone, for post-Wo LN) ----------------
__global__ __launch_bounds__(256) void ln_kernel(const float* __restrict__ in,
                                                 const float* __restrict__ g,
                                                 const float* __restrict__ be,
                                                 bf16_t* __restrict__ out) {
  const int row = blockIdx.x, t = threadIdx.x;
  const float4 xv = ((const float4*)(in + (long)row * 1024))[t];
  float s1 = xv.x + xv.y + xv.z + xv.w;
  float s2 = xv.x * xv.x + xv.y * xv.y + xv.z * xv.z + xv.w * xv.w;
#pragma unroll
  for (int m = 1; m < 64; m <<= 1) {
    s1 += __shfl_xor(s1, m);
    s2 += __shfl_xor(s2, m);
  }
  __shared__ float r1[4], r2[4];
  if ((t & 63) == 0) { r1[t >> 6] = s1; r2[t >> 6] = s2; }
  __syncthreads();
  s1 = r1[0] + r1[1] + r1[2] + r1[3];
  s2 = r2[0] + r2[1] + r2[2] + r2[3];
  const float mean = s1 * (1.0f / 1024.0f);
  float var = s2 * (1.0f / 1024.0f) - mean * mean;
  const float rstd = rsqrtf(fmaxf(var, 0.0f) + 1e-5f);
  const float4 gv = ((const float4*)g)[t];
  const float4 bv = ((const float4*)be)[t];
  bf16x4 o;
  o[0] = (bf16_t)((xv.x - mean) * rstd * gv.x + bv.x);
  o[1] = (bf16_t)((xv.y - mean) * rstd * gv.y + bv.y);
  o[2] = (bf16_t)((xv.z - mean) * rstd * gv.z + bv.z);
  o[3] = (bf16_t)((xv.w - mean) * rstd * gv.w + bv.w);
  *(bf16x4*)(out + (long)row * 1024 + t * 4) = o;
}

// ---------------- W2 split-K reduce: out += sum(partials) + b2 ----------------
__global__ __launch_bounds__(256) void reduce_w2(const bf16_t* __restrict__ part,
                                                 const float* __restrict__ b2,
                                                 float* __restrict__ out) {
  const long base = (long)blockIdx.x * 1024 + threadIdx.x * 4;
  float4 o = *(float4*)(out + base);
  const float4 bb = ((const float4*)b2)[threadIdx.x];
  float s0 = 0.0f, s1 = 0.0f, s2 = 0.0f, s3 = 0.0f;
#pragma unroll
  for (int s = 0; s < 4; s++) {
    bf16x4 p = *(const bf16x4*)(part + ((long)s << 22) + base);
    s0 += (float)p[0];
    s1 += (float)p[1];
    s2 += (float)p[2];
    s3 += (float)p[3];
  }
  o.x += s0 + bb.x;
  o.y += s1 + bb.y;
  o.z += s2 + bb.z;
  o.w += s3 + bb.w;
  *(float4*)(out + base) = o;
}

// -------- attn T-split combine: ob = (N0+N1)/(d0+d1), hm-64 -> concat layout --------
// grid 4096 (b*2048+s rows), 256 threads; thread t -> cols [t*4, t*4+4)
__global__ __launch_bounds__(256) void attn_combine(const bf16_t* __restrict__ opart,
                                                    const float* __restrict__ dpart,
                                                    bf16_t* __restrict__ ob) {
  const int bid = blockIdx.x, t = threadIdx.x;
  const int b = bid >> 11, s = bid & 2047;
  const int col = t * 4, h = col >> 6, p = col & 63;
  const int bh = b * 16 + h;
  const float d = dpart[bh * 2048 + s] + dpart[65536 + bh * 2048 + s];
  const float inv = 1.0f / d;
  const long pbase = ((long)bh * 2048 + s) * 64 + p;
  bf16x4 p0 = *(const bf16x4*)(opart + pbase);
  bf16x4 p1 = *(const bf16x4*)(opart + 4194304 + pbase);
  bf16x4 o;
#pragma unroll
  for (int r = 0; r < 4; r++) o[r] = (bf16_t)(((float)p0[r] + (float)p1[r]) * inv);
  *(bf16x4*)(ob + (long)bid * 1024 + col) = o;
}

// ====== gemm256: 256x256 tile, 8 waves, BK=64 as 2 kk-halves, 4 phases/K-tile ======
// EPI 2: gelu(bias)->bf16 (W1) ; EPI 7: split-K bf16 partials (W2)
template <int EPI, int RW>
__global__ __launch_bounds__(512, 2) void gemm256(const bf16_t* __restrict__ A,
                                                  const bf16_t* __restrict__ Bt,
                                                  const float* __restrict__ bias,
                                                  void* __restrict__ Cout,
                                                  int M, int N, int K) {
  __shared__ bf16_t a_l[2][2][256 * 32];
  __shared__ bf16_t b_l[2][2][256 * 32];
  const int tid = threadIdx.x, l = tid & 63, wid = tid >> 6;
  const int wr = wid >> 2, wc = wid & 3;
  const int lr = l & 15, lg = l >> 4;
  const int nwg = gridDim.x * gridDim.y * gridDim.z;
  const int orig = (blockIdx.z * gridDim.y + blockIdx.y) * gridDim.x + blockIdx.x;
  int bx, by, ks = 0;
  if (EPI == 7) {
    const int lid = (orig & 7) * (nwg >> 3) + (orig >> 3);
    bx = lid % gridDim.x;
    by = (lid / gridDim.x) % gridDim.y;
    ks = lid / (gridDim.x * gridDim.y);
  } else {
    const int cpx = nwg >> 3;
    const int xcd = orig & 7, ii = orig >> 3;
    const int rpr = gridDim.x / RW;
    bx = (xcd % rpr) * RW + (ii % RW);
    by = (xcd / rpr) * (cpx / RW) + (ii / RW);
  }
  const int m0 = by * 256, n0 = bx * 256;
  const long kbase = (EPI == 7) ? (long)ks << 10 : 0;
  const int nt = (EPI == 7) ? 16 : (K >> 6);
  const int sr0 = tid >> 2, sr1 = 128 + (tid >> 2);
  const int sch2 = ((tid & 3) ^ ((tid >> 3) & 3)) * 8;
  const int sl0 = sr0 * 32 + (tid & 3) * 8;
  const int sl1 = sr1 * 32 + (tid & 3) * 8;
#define STG_A(bufi, kki, kcol)                                                  \
  do {                                                                          \
    gload16(A + (long)(m0 + sr0) * K + (kcol) + sch2, &a_l[bufi][kki][sl0]);    \
    gload16(A + (long)(m0 + sr1) * K + (kcol) + sch2, &a_l[bufi][kki][sl1]);    \
  } while (0)
#define STG_B(bufi, kki, kcol)                                                  \
  do {                                                                          \
    gload16(Bt + (long)(n0 + sr0) * K + (kcol) + sch2, &b_l[bufi][kki][sl0]);   \
    gload16(Bt + (long)(n0 + sr1) * K + (kcol) + sch2, &b_l[bufi][kki][sl1]);   \
  } while (0)
  const int ch = (lg ^ ((lr >> 1) & 3)) * 8;
  f32x4 acc[8][4] = {};
  bf16x8 af[8], bf2[2];
  STG_A(0, 0, kbase + 0); STG_B(0, 0, kbase + 0);
  STG_A(0, 1, kbase + 32); STG_B(0, 1, kbase + 32);
  STG_A(1, 0, kbase + 64); STG_B(1, 0, kbase + 64);
  asm volatile("s_waitcnt vmcnt(8)" ::: "memory");
  __builtin_amdgcn_s_barrier();
  for (int t = 0; t < nt; t++) {
    const int buf = t & 1, nbuf = buf ^ 1;
    const long kc = kbase + (long)t * 64;
#define RD_A(kki)                                                      \
  _Pragma("unroll") for (int m = 0; m < 8; m++) af[m] =                \
      *(const bf16x8*)&a_l[buf][kki][(wr * 128 + m * 16 + lr) * 32 + ch];
#define RD_B(kki, nh)                                                  \
  _Pragma("unroll") for (int j = 0; j < 2; j++) bf2[j] =               \
      *(const bf16x8*)&b_l[buf][kki][(wc * 64 + ((nh)*2 + j) * 16 + lr) * 32 + ch];
#define MM(nh)                                                         \
  __builtin_amdgcn_s_setprio(1);                                       \
  _Pragma("unroll") for (int m = 0; m < 8; m++) {                      \
    acc[m][(nh)*2 + 0] = mfma16(af[m], bf2[0], acc[m][(nh)*2 + 0]);    \
    acc[m][(nh)*2 + 1] = mfma16(af[m], bf2[1], acc[m][(nh)*2 + 1]);    \
  }                                                                    \
  __builtin_amdgcn_s_setprio(0);
    RD_A(0); RD_B(0, 0);
    if (t + 1 < nt) { STG_A(nbuf, 1, kc + 96); }
    __builtin_amdgcn_s_barrier();
    asm volatile("s_waitcnt lgkmcnt(0)" ::: "memory");
    __builtin_amdgcn_sched_barrier(0);
    MM(0);
    __builtin_amdgcn_s_barrier();
    RD_B(0, 1);
    if (t + 1 < nt) { STG_B(nbuf, 1, kc + 96); }
    if (t + 1 < nt) asm volatile("s_waitcnt vmcnt(8)" ::: "memory");
    else            asm volatile("s_waitcnt vmcnt(0)" ::: "memory");
    __builtin_amdgcn_s_barrier();
    asm volatile("s_waitcnt lgkmcnt(0)" ::: "memory");
    __builtin_amdgcn_sched_barrier(0);
    MM(1);
    __builtin_amdgcn_s_barrier();
    RD_A(1); RD_B(1, 0);
    if (t + 2 < nt) { STG_A(buf, 0, kc + 128); }
    __builtin_amdgcn_s_barrier();
    asm volatile("s_waitcnt lgkmcnt(0)" ::: "memory");
    __builtin_amdgcn_sched_barrier(0);
    MM(0);
    __builtin_amdgcn_s_barrier();
    RD_B(1, 1);
    if (t + 2 < nt) { STG_B(buf, 0, kc + 128); }
    if (t + 2 < nt)      asm volatile("s_waitcnt vmcnt(8)" ::: "memory");
    else if (t + 1 < nt) asm volatile("s_waitcnt vmcnt(4)" ::: "memory");
    __builtin_amdgcn_s_barrier();
    asm volatile("s_waitcnt lgkmcnt(0)" ::: "memory");
    __builtin_amdgcn_sched_barrier(0);
    MM(1);
    __builtin_amdgcn_s_barrier();
  }
#undef RD_A
#undef RD_B
#undef MM
#undef STG_A
#undef STG_B
#pragma unroll
  for (int m = 0; m < 8; m++)
#pragma unroll
    for (int n = 0; n < 4; n++) {
      const int row_b = m0 + wr * 128 + m * 16 + lg * 4;
      const int col = n0 + wc * 64 + n * 16 + lr;
      if (EPI == 2) {
        const float bia = bias[col];
#pragma unroll
        for (int r = 0; r < 4; r++) {
          const long idx = (long)(row_b + r) * N + col;
          ((bf16_t*)Cout)[idx] = (bf16_t)gelu_f(acc[m][n][r] + bia);
        }
      } else if (EPI == 7) {
        bf16_t* part = (bf16_t*)Cout + ((long)ks << 22);
#pragma unroll
        for (int r = 0; r < 4; r++)
          part[(long)(row_b + r) * N + col] = (bf16_t)acc[m][n][r];
      }
    }
}

// ---------------- GEMM BK=32 (QKV): 3-buffer, counted vmcnt, 2D XCD regions ----------------
template <int EPI, int BN, int RW>
__global__ __launch_bounds__(256) void gemm32(const bf16_t* __restrict__ A,
                                              const bf16_t* __restrict__ A2,
                                              const bf16_t* __restrict__ Bt,
                                              const float* __restrict__ bias,
                                              const float* __restrict__ biasB,
                                              const float* __restrict__ biasC,
                                              bf16_t* __restrict__ aux,
                                              void* __restrict__ Cout,
                                              int M, int N, int K) {
  constexpr int NF = BN / 32;
  constexpr int NBI = BN / 64;
  __shared__ bf16_t a_lds[3][128 * 32];
  __shared__ bf16_t b_lds[3][BN * 32];
  const int tid = threadIdx.x, l = tid & 63, w = tid >> 6;
  const int wr = w >> 1, wc = w & 1;
  const int nwg = gridDim.x * gridDim.y;
  const int orig = blockIdx.y * gridDim.x + blockIdx.x;
  const int cpx = nwg >> 3;
  const int xcd = orig & 7, ii = orig >> 3;
  const int rpr = gridDim.x / RW;
  const int bx = (xcd % rpr) * RW + (ii % RW);
  const int by = (xcd / rpr) * (cpx / RW) + (ii / RW);
  const int m0 = by * 128, n0 = bx * BN;
  const bf16_t* Ause = (EPI == 5 && n0 >= 1024) ? A2 : A;
  const int lr = l & 15, lg = l >> 4;
  long a_src[2];
  int a_dst[2];
#pragma unroll
  for (int i = 0; i < 2; i++) {
    const int row = i * 64 + (tid >> 2);
    const int sc = ((tid & 3) ^ ((row >> 1) & 3)) * 8;
    a_src[i] = (long)(m0 + row) * K + sc;
    a_dst[i] = (i * 64 + w * 16) * 32;
  }
  long b_src[NBI];
#pragma unroll
  for (int i = 0; i < NBI; i++) {
    const int row = i * 64 + (tid >> 2);
    const int sc = ((tid & 3) ^ ((row >> 1) & 3)) * 8;
    b_src[i] = (long)(n0 + row) * K + sc;
  }
  const int nk = K >> 5;
  f32x4 acc[4][NF] = {};
#pragma unroll
  for (int tt = 0; tt < 2; tt++) {
#pragma unroll
    for (int i = 0; i < 2; i++) gload16(Ause + a_src[i] + tt * 32, &a_lds[tt][a_dst[i]]);
#pragma unroll
    for (int i = 0; i < NBI; i++) gload16(Bt + b_src[i] + tt * 32, &b_lds[tt][a_dst[i]]);
  }
  int cu = 0;
  for (int t = 0; t < nk; t++) {
    if (t + 1 < nk) asm volatile("s_waitcnt vmcnt(4)" ::: "memory");
    else            asm volatile("s_waitcnt vmcnt(0)" ::: "memory");
    __builtin_amdgcn_s_barrier();
    __builtin_amdgcn_sched_barrier(0);
    if (t + 2 < nk) {
      const long k0 = (long)(t + 2) * 32;
      const int nb = cu >= 1 ? cu - 1 : 2;
#pragma unroll
      for (int i = 0; i < 2; i++) gload16(Ause + a_src[i] + k0, &a_lds[nb][a_dst[i]]);
#pragma unroll
      for (int i = 0; i < NBI; i++) gload16(Bt + b_src[i] + k0, &b_lds[nb][a_dst[i]]);
    }
    const char* ab = (const char*)&a_lds[cu][0];
    const char* bb = (const char*)&b_lds[cu][0];
    bf16x8 af[4], bfr[NF];
#pragma unroll
    for (int m = 0; m < 4; m++) {
      const int row = wr * 64 + m * 16 + lr;
      af[m] = *(const bf16x8*)(ab + row * 64 + 16 * (lg ^ ((row >> 1) & 3)));
    }
#pragma unroll
    for (int n = 0; n < NF; n++) {
      const int row = wc * (BN / 2) + n * 16 + lr;
      bfr[n] = *(const bf16x8*)(bb + row * 64 + 16 * (lg ^ ((row >> 1) & 3)));
    }
    __builtin_amdgcn_s_setprio(1);
#pragma unroll
    for (int m = 0; m < 4; m++)
#pragma unroll
      for (int n = 0; n < NF; n++) acc[m][n] = mfma16(af[m], bfr[n], acc[m][n]);
    __builtin_amdgcn_s_setprio(0);
    cu = cu < 2 ? cu + 1 : 0;
  }
#pragma unroll
  for (int m = 0; m < 4; m++)
#pragma unroll
    for (int n = 0; n < NF; n++) {
      const int row_b = m0 + wr * 64 + m * 16 + (l >> 4) * 4;
      const int col = n0 + wc * (BN / 2) + n * 16 + lr;
      if (EPI == 5) {
        if (col < 1024) {
          const float bia = bias[col];
#pragma unroll
          for (int r = 0; r < 4; r++)
            ((bf16_t*)Cout)[hmi(row_b + r, col)] = (bf16_t)((acc[m][n][r] + bia) * QSCALE);
        } else if (col < 2048) {
          const float bia = biasB[col - 1024];
#pragma unroll
          for (int r = 0; r < 4; r++)
            ((bf16_t*)Cout + 4194304)[hmi(row_b + r, col - 1024)] =
                (bf16_t)(acc[m][n][r] + bia);
        } else {
          const int vcol = col - 2048;
          const float bia = biasC[vcol];
          bf16x4 vv;
#pragma unroll
          for (int r = 0; r < 4; r++) vv[r] = (bf16_t)(acc[m][n][r] + bia);
          const int bb2 = row_b >> 11, tt = row_b & 2047;
          *(bf16x4*)&aux[(((long)(bb2 << 4) + (vcol >> 6)) * 64 + (vcol & 63)) * 2048 + tt] = vv;
        }
      }
    }
}

// ---------------- GEMM BK=64 (Wo: BN=64, 48KB LDS): EPI 1 = bias+res -> fp32 ----------------
template <int EPI, int BN>
__global__ __launch_bounds__(256) void gemm64(const bf16_t* __restrict__ A,
                                              const bf16_t* __restrict__ Bt,
                                              const float* __restrict__ bias,
                                              const float* __restrict__ res,
                                              void* __restrict__ Cout,
                                              int M, int N, int K) {
  constexpr int NF = BN / 32;
  constexpr int NBI = BN / 32;
  __shared__ bf16_t a_lds[2][128 * 64];
  __shared__ bf16_t b_lds[2][BN * 64];
  const int tid = threadIdx.x, l = tid & 63, w = tid >> 6;
  const int wr = w >> 1, wc = w & 1;
  const int nwg = gridDim.x * gridDim.y;
  const int orig = blockIdx.y * gridDim.x + blockIdx.x;
  const int lid = (orig & 7) * (nwg >> 3) + (orig >> 3);
  const int bx = lid % gridDim.x, by = lid / gridDim.x;
  const int m0 = by * 128, n0 = bx * BN;
  const int lr = l & 15, lg = l >> 4;
  long a_src[4];
  int ldst[4];
#pragma unroll
  for (int i = 0; i < 4; i++) {
    const int row = i * 32 + w * 8 + (l >> 3);
    const int sc = ((l & 7) ^ (row & 7)) * 8;
    a_src[i] = (long)(m0 + row) * K + sc;
    ldst[i] = (i * 32 + w * 8) * 64;
  }
  long b_src[NBI];
#pragma unroll
  for (int i = 0; i < NBI; i++) {
    const int row = i * 32 + w * 8 + (l >> 3);
    const int sc = ((l & 7) ^ (row & 7)) * 8;
    b_src[i] = (long)(n0 + row) * K + sc;
  }
  const int nk = K >> 6;
  f32x4 acc[4][NF] = {};
#pragma unroll
  for (int i = 0; i < 4; i++) gload16(A + a_src[i], &a_lds[0][ldst[i]]);
#pragma unroll
  for (int i = 0; i < NBI; i++) gload16(Bt + b_src[i], &b_lds[0][ldst[i]]);
  __syncthreads();
  const int sw = (lr & 7) << 4;
  int cur = 0;
  for (int t = 0; t < nk; t++) {
    if (t + 1 < nk) {
      const long k0 = (long)(t + 1) * 64;
#pragma unroll
      for (int i = 0; i < 4; i++) gload16(A + a_src[i] + k0, &a_lds[cur ^ 1][ldst[i]]);
#pragma unroll
      for (int i = 0; i < NBI; i++) gload16(Bt + b_src[i] + k0, &b_lds[cur ^ 1][ldst[i]]);
    }
    const char* ab = (const char*)&a_lds[cur][0];
    const char* bb = (const char*)&b_lds[cur][0];
    bf16x8 af[4][2], bfr[NF][2];
#pragma unroll
    for (int m = 0; m < 4; m++) {
      const int rb = (wr * 64 + m * 16 + lr) * 128;
      af[m][0] = *(const bf16x8*)(ab + rb + ((16 * lg) ^ sw));
      af[m][1] = *(const bf16x8*)(ab + rb + ((16 * lg + 64) ^ sw));
    }
#pragma unroll
    for (int n = 0; n < NF; n++) {
      const int rb = (wc * (BN / 2) + n * 16 + lr) * 128;
      bfr[n][0] = *(const bf16x8*)(bb + rb + ((16 * lg) ^ sw));
      bfr[n][1] = *(const bf16x8*)(bb + rb + ((16 * lg + 64) ^ sw));
    }
    __builtin_amdgcn_s_setprio(1);
#pragma unroll
    for (int kk = 0; kk < 2; kk++)
#pragma unroll
      for (int m = 0; m < 4; m++)
#pragma unroll
        for (int n = 0; n < NF; n++)
          acc[m][n] = mfma16(af[m][kk], bfr[n][kk], acc[m][n]);
    __builtin_amdgcn_s_setprio(0);
    __syncthreads();
    cur ^= 1;
  }
#pragma unroll
  for (int m = 0; m < 4; m++)
#pragma unroll
    for (int n = 0; n < NF; n++) {
      const int row_b = m0 + wr * 64 + m * 16 + (l >> 4) * 4;
      const int col = n0 + wc * (BN / 2) + n * 16 + lr;
      const float bia = bias[col];
#pragma unroll
      for (int r = 0; r < 4; r++) {
        const long idx = (long)(row_b + r) * N + col;
        ((float*)Cout)[idx] = acc[m][n][r] + bia + res[idx];
      }
    }
}

// ---------------- fused attention v8: QBLK=128, T-split x2 (exact-sum partials) --------
// blockIdx.z selects t-half [z*1024, z*1024+1024). Max-free softmax => partials over
// disjoint t-ranges combine by plain addition (no rescale). Numerators stored bf16,
// denominators fp32; attn_combine normalizes.
__global__ __launch_bounds__(256) void attn_kernel(const bf16_t* __restrict__ qhm,
                                                   const bf16_t* __restrict__ khm,
                                                   const bf16_t* __restrict__ vtg,
                                                   bf16_t* __restrict__ opart,
                                                   float* __restrict__ dpart,
                                                   const int* __restrict__ maskp) {
  const int T = 2048;
  __shared__ bf16_t k_lds[2][64 * 64];
  __shared__ bf16_t vt_lds[2][64 * 64];
  __shared__ bf16_t p_lds[4 * 32 * 72];
  const int bh = blockIdx.x;
  const int q0 = blockIdx.y * 128;
  const int z = blockIdx.z;  // t-half
  const int tg0 = z * 16;    // first global t-tile of this half
  const int tid = threadIdx.x, l = tid & 63, w = tid >> 6;
  const int lr = l & 15, lg = l >> 4, lg4 = lg * 4;
  const int srow0 = q0 + w * 32 + lr;
  const bf16_t* kbase = khm + (long)bh * T * 64;
  const bf16_t* vbase = vtg + (long)bh * 64 * T;
  bf16x8 qf[2][2];
#pragma unroll
  for (int g = 0; g < 2; g++) {
    const bf16_t* qr = qhm + ((long)bh * 2048 + srow0 + g * 16) * 64 + lg * 8;
    qf[g][0] = *(const bf16x8*)qr;
    qf[g][1] = *(const bf16x8*)(qr + 32);
  }
  bf16_t* pl = &p_lds[w * 32 * 72];
  float lpart[2] = {0.0f, 0.0f};
  f32x4 oat[4][2] = {};

  const int swz = (lr & 7) << 4;
  const int fo0 = lr * 128 + ((16 * lg) ^ swz);
  const int fo1 = lr * 128 + ((64 + 16 * lg) ^ swz);

  const bool do_mask = (maskp[0] != 0);
  const int nM = do_mask ? (q0 >> 6) : 0;  // GLOBAL tile index bound for full-mask

  const int sch = l & 7, srow8 = l >> 3;
  int cur = 0;
  {
    const int t0 = tg0 << 6;
    const bool needV = (tg0 >= nM);
#pragma unroll
    for (int i = 0; i < 2; i++) {
      const int row = (i * 4 + w) * 8 + srow8;
      const int sc = (sch ^ (row & 7)) * 8;
      gload16(kbase + (long)(t0 + row) * 64 + sc, &k_lds[0][(i * 4 + w) * 512]);
      if (needV) gload16(vbase + (long)row * 2048 + t0 + sc, &vt_lds[0][(i * 4 + w) * 512]);
    }
  }
  __syncthreads();

  for (int tl = 0; tl < 16; tl++) {
    const int tg = tg0 + tl;
    const int t0 = tg << 6;
    const int mode = (tg < nM) ? 0 : ((do_mask && tg < nM + 2) ? 1 : 2);
    if (tl + 1 < 16) {
      const int t1 = (tg + 1) << 6;
      const bool needV = (tg + 1) >= nM;
#pragma unroll
      for (int i = 0; i < 2; i++) {
        const int row = (i * 4 + w) * 8 + srow8;
        const int sc = (sch ^ (row & 7)) * 8;
        gload16(kbase + (long)(t1 + row) * 64 + sc, &k_lds[cur ^ 1][(i * 4 + w) * 512]);
        if (needV)
          gload16(vbase + (long)row * 2048 + t1 + sc, &vt_lds[cur ^ 1][(i * 4 + w) * 512]);
      }
    }
    const char* kb = (const char*)&k_lds[cur][0];
    f32x4 sacc[4][2];
    __builtin_amdgcn_s_setprio(1);
#pragma unroll
    for (int n = 0; n < 4; n++) {
      bf16x8 kf0 = *(const bf16x8*)(kb + n * 2048 + fo0);
      bf16x8 kf1 = *(const bf16x8*)(kb + n * 2048 + fo1);
#pragma unroll
      for (int g = 0; g < 2; g++) {
        f32x4 zz = {0.0f, 0.0f, 0.0f, 0.0f};
        zz = mfma16(kf0, qf[g][0], zz);
        sacc[n][g] = mfma16(kf1, qf[g][1], zz);
      }
    }
    __builtin_amdgcn_s_setprio(0);
    float pv[2][4][4];
#pragma unroll
    for (int g = 0; g < 2; g++) {
      float psn[4];
#pragma unroll
      for (int n = 0; n < 4; n++) {
        pv[g][n][0] = exp2_fast(sacc[n][g][0]);
        pv[g][n][1] = exp2_fast(sacc[n][g][1]);
        pv[g][n][2] = exp2_fast(sacc[n][g][2]);
        pv[g][n][3] = exp2_fast(sacc[n][g][3]);
        psn[n] = (pv[g][n][0] + pv[g][n][1]) + (pv[g][n][2] + pv[g][n][3]);
      }
      lpart[g] += (psn[0] + psn[1]) + (psn[2] + psn[3]);
    }
    if (mode > 0) {
#pragma unroll
      for (int g = 0; g < 2; g++)
#pragma unroll
        for (int n = 0; n < 4; n++) {
          bf16x4 pk;
#pragma unroll
          for (int r = 0; r < 4; r++) {
            float v = pv[g][n][r];
            if (mode == 1 && (t0 + n * 16 + lg4 + r) <= srow0 + g * 16) v = 0.0f;
            pk[r] = (bf16_t)v;
          }
          *(bf16x4*)&pl[(g * 16 + lr) * 72 + n * 16 + lg4] = pk;
        }
      const char* vtb = (const char*)&vt_lds[cur][0];
      __builtin_amdgcn_s_setprio(1);
#pragma unroll
      for (int kk = 0; kk < 2; kk++) {
        bf16x8 pb0 = *(bf16x8*)&pl[lr * 72 + kk * 32 + lg * 8];
        bf16x8 pb1 = *(bf16x8*)&pl[(16 + lr) * 72 + kk * 32 + lg * 8];
        const int fkk = lr * 128 + ((kk * 64 + 16 * lg) ^ swz);
#pragma unroll
        for (int np = 0; np < 4; np++) {
          bf16x8 vtf = *(const bf16x8*)(vtb + np * 2048 + fkk);
          oat[np][0] = mfma16(vtf, pb0, oat[np][0]);
          oat[np][1] = mfma16(vtf, pb1, oat[np][1]);
        }
      }
      __builtin_amdgcn_s_setprio(0);
    }
    __syncthreads();
    cur ^= 1;
  }
  // epilogue: write RAW numerator (bf16) + partial denominator (fp32); no normalize.
#pragma unroll
  for (int g = 0; g < 2; g++) {
    float lsum = lpart[g];
    lsum += __shfl_xor(lsum, 16);
    lsum += __shfl_xor(lsum, 32);
    if (lg == 0)  // one lane per row writes the denom
      dpart[z * 65536 + bh * 2048 + q0 + w * 32 + g * 16 + lr] = lsum;
  }
#pragma unroll
  for (int g = 0; g < 2; g++)
#pragma unroll
    for (int np = 0; np < 4; np++) {
      bf16x4 o4;
#pragma unroll
      for (int r = 0; r < 4; r++) o4[r] = (bf16_t)oat[np][g][r];
      *(bf16x4*)&pl[(g * 16 + lr) * 72 + np * 16 + lg4] = o4;
    }
  const int es = l >> 2, ec = (l & 3) * 16;
  bf16_t* obase = opart + (long)z * 4194304;
#pragma unroll
  for (int g = 0; g < 2; g++) {
    bf16x8 o0 = *(bf16x8*)&pl[(g * 16 + es) * 72 + ec];
    bf16x8 o1 = *(bf16x8*)&pl[(g * 16 + es) * 72 + ec + 8];
    bf16_t* orow = obase + ((long)bh * 2048 + q0 + w * 32 + g * 16 + es) * 64 + ec;
    *(bf16x8*)&orow[0] = o0;
    *(bf16x8*)&orow[8] = o1;
  }
}

extern "C" void kernel_launch(void* const* d_in, const int* in_sizes, int n_in,
                              void* d_out, int out_size, void* d_ws, size_t ws_size,
                              hipStream_t stream) {
  const float* x = (const float*)d_in[0];
  const float* y = (const float*)d_in[1];
  const float* gxg = (const float*)d_in[2];
  const float* gxb = (const float*)d_in[3];
  const float* gyg = (const float*)d_in[4];
  const float* gyb = (const float*)d_in[5];
  const float* Wq = (const float*)d_in[6];
  const float* bq = (const float*)d_in[7];
  const float* Wk = (const float*)d_in[8];
  const float* bk = (const float*)d_in[9];
  const float* Wv = (const float*)d_in[10];
  const float* bv = (const float*)d_in[11];
  const float* Wo = (const float*)d_in[12];
  const float* bo = (const float*)d_in[13];
  const float* gdg = (const float*)d_in[14];
  const float* gdb = (const float*)d_in[15];
  const float* W1 = (const float*)d_in[16];
  const float* b1 = (const float*)d_in[17];
  const float* W2 = (const float*)d_in[18];
  const float* b2 = (const float*)d_in[19];
  const int* maskp = (const int*)d_in[20];
  float* out = (float*)d_out;

  char* ws = (char*)d_ws;
  const long MB = 1024 * 1024;
  bf16_t* xn = (bf16_t*)(ws + 0);
  bf16_t* yn = (bf16_t*)(ws + 8 * MB);
  bf16_t* WqkvT = (bf16_t*)(ws + 16 * MB);
  bf16_t* WoT = (bf16_t*)(ws + 22 * MB);
  bf16_t* W1T = (bf16_t*)(ws + 24 * MB);
  bf16_t* W2T = (bf16_t*)(ws + 32 * MB);
  bf16_t* qhm = (bf16_t*)(ws + 40 * MB);
  bf16_t* vTb = (bf16_t*)(ws + 64 * MB);
  // lifetimes: xn/yn/WqkvT dead after QKV -> opart [0,16MB), dpart [16,16.5MB)
  bf16_t* opart = (bf16_t*)(ws + 0);
  float* dpart = (float*)(ws + 16 * MB);
  bf16_t* ob = (bf16_t*)(ws + 56 * MB);  // [56,64) free; dead before hb overwrite
  bf16_t* xd = (bf16_t*)(ws + 8 * MB);   // written by LN after ob consumed? no: after Wo
  bf16_t* hb = (bf16_t*)(ws + 40 * MB);  // [40,72): qhm/khm/ob/vTb dead by W1
  bf16_t* w2part = (bf16_t*)(ws + 0);    // [0,32MB): opart/dpart/xd dead by W2
  bf16_t* khm = qhm + 4194304;

  prep_all<<<11264, 256, 0, stream>>>(Wq, Wk, Wv, Wo, W1, W2, WqkvT, WoT, W1T, W2T, x, y, gxg,
                                      gxb, gyg, gyb, xn, yn);
  gemm32<5, 128, 12><<<dim3(24, 32), 256, 0, stream>>>(xn, yn, WqkvT, bq, bk, bv, vTb, qhm,
                                                       4096, 3072, 1024);
  // T-split attention (1024 blocks) + exact-sum combine
  attn_kernel<<<dim3(32, 16, 2), 256, 0, stream>>>(qhm, khm, vTb, opart, dpart, maskp);
  attn_combine<<<4096, 256, 0, stream>>>(opart, dpart, ob);
  gemm64<1, 64><<<dim3(16, 32), 256, 0, stream>>>(ob, WoT, bo, x, out, 4096, 1024, 1024);
  ln_kernel<<<4096, 256, 0, stream>>>(out, gdg, gdb, xd);
  gemm256<2, 4><<<dim3(16, 16), 512, 0, stream>>>(xd, W1T, b1, hb, 4096, 4096, 1024);
  gemm256<7, 4><<<dim3(4, 16, 4), 512, 0, stream>>>(hb, W2T, nullptr, w2part, 4096, 1024, 4096);
  reduce_w2<<<4096, 256, 0, stream>>>(w2part, b2, out);
}

// Round 18
// 224.456 us; speedup vs baseline: 1.0401x; 1.0401x over previous
//
#include <hip/hip_runtime.h>
#include <hip/hip_bf16.h>
#include <math.h>

// B=2, SX=SY=2048, XD=YD=1024, P=64, H=16, MULT=4
typedef __bf16 bf16_t;
typedef __bf16 bf16x8 __attribute__((ext_vector_type(8)));
typedef __bf16 bf16x4 __attribute__((ext_vector_type(4)));
typedef float f32x4 __attribute__((ext_vector_type(4)));

#define QSCALE 0.18033688011112042f /* 0.125 * log2(e): scores in log2 units */

static __device__ __forceinline__ f32x4 mfma16(bf16x8 a, bf16x8 b, f32x4 c) {
  return __builtin_amdgcn_mfma_f32_16x16x32_bf16(a, b, c, 0, 0, 0);
}

static __device__ __forceinline__ float exp2_fast(float x) {
  float r;
  asm("v_exp_f32 %0, %1" : "=v"(r) : "v"(x));
  return r;
}

// tanh-form GELU: 0.5x(1+tanh(u)) = x*e/(e+1), e = exp(2u), u = c1*x + c2*x^3.
static __device__ __forceinline__ float gelu_f(float x) {
  const float u = x * (0.7978845608028654f + 0.03567740813636141f * x * x);
  const float a = fminf(u * 2.885390081777927f, 126.0f);
  const float e = exp2_fast(a);
  float r;
  asm("v_rcp_f32 %0, %1" : "=v"(r) : "v"(e + 1.0f));
  return x * e * r;
}

typedef __attribute__((address_space(1))) const void as1_void;
typedef __attribute__((address_space(3))) void as3_void;
static __device__ __forceinline__ void gload16(const void* g, void* s) {
  __builtin_amdgcn_global_load_lds((as1_void*)g, (as3_void*)s, 16, 0, 0);
}

// head-major index: [b][h][s][p] from (row = b*2048+s, col = h*64+p)
static __device__ __forceinline__ long hmi(int row, int col) {
  return ((((long)(row >> 11) * 16 + (col >> 6)) * 2048) + (row & 2047)) * 64 + (col & 63);
}

// -------- merged prep: 6 weight transposes + both input LayerNorms, one launch --------
__global__ __launch_bounds__(256) void prep_all(
    const float* __restrict__ Wq, const float* __restrict__ Wk, const float* __restrict__ Wv,
    const float* __restrict__ Wo, const float* __restrict__ W1, const float* __restrict__ W2,
    bf16_t* __restrict__ WqkvT, bf16_t* __restrict__ WoT, bf16_t* __restrict__ W1T,
    bf16_t* __restrict__ W2T, const float* __restrict__ x, const float* __restrict__ y,
    const float* __restrict__ gx, const float* __restrict__ bex, const float* __restrict__ gy,
    const float* __restrict__ bey, bf16_t* __restrict__ xn, bf16_t* __restrict__ yn) {
  const int bid = blockIdx.x;
  if (bid >= 3072) {
    const int lrow = bid - 3072;
    const float* in = lrow < 4096 ? x : y;
    const float* g = lrow < 4096 ? gx : gy;
    const float* be = lrow < 4096 ? bex : bey;
    bf16_t* out = lrow < 4096 ? xn : yn;
    const int row = lrow & 4095;
    const int t = threadIdx.x;
    const float4 xv = ((const float4*)(in + (long)row * 1024))[t];
    float s1 = xv.x + xv.y + xv.z + xv.w;
    float s2 = xv.x * xv.x + xv.y * xv.y + xv.z * xv.z + xv.w * xv.w;
#pragma unroll
    for (int m = 1; m < 64; m <<= 1) {
      s1 += __shfl_xor(s1, m);
      s2 += __shfl_xor(s2, m);
    }
    __shared__ float r1[4], r2[4];
    if ((t & 63) == 0) { r1[t >> 6] = s1; r2[t >> 6] = s2; }
    __syncthreads();
    s1 = r1[0] + r1[1] + r1[2] + r1[3];
    s2 = r2[0] + r2[1] + r2[2] + r2[3];
    const float mean = s1 * (1.0f / 1024.0f);
    float var = s2 * (1.0f / 1024.0f) - mean * mean;
    const float rstd = rsqrtf(fmaxf(var, 0.0f) + 1e-5f);
    const float4 gv = ((const float4*)g)[t];
    const float4 bv = ((const float4*)be)[t];
    bf16x4 o;
    o[0] = (bf16_t)((xv.x - mean) * rstd * gv.x + bv.x);
    o[1] = (bf16_t)((xv.y - mean) * rstd * gv.y + bv.y);
    o[2] = (bf16_t)((xv.z - mean) * rstd * gv.z + bv.z);
    o[3] = (bf16_t)((xv.w - mean) * rstd * gv.w + bv.w);
    *(bf16x4*)(out + (long)row * 1024 + t * 4) = o;
    return;
  }
  const float* inp;
  bf16_t* outp;
  int istride, ostride, i0, j0;
  if (bid < 768) {
    const int wsel = bid >> 8, rem = bid & 255;
    const int h = rem >> 4, xt = rem & 15;
    const float* W = wsel == 0 ? Wq : (wsel == 1 ? Wk : Wv);
    inp = W + h * 65536;
    outp = WqkvT + (long)wsel * 1048576 + h * 65536;
    istride = 64; ostride = 1024; i0 = xt * 64; j0 = 0;
  } else if (bid < 1024) {
    const int rem = bid - 768;
    inp = Wo; outp = WoT; istride = 1024; ostride = 1024;
    i0 = (rem & 15) * 64; j0 = (rem >> 4) * 64;
  } else if (bid < 2048) {
    const int rem = bid - 1024;
    inp = W1; outp = W1T; istride = 4096; ostride = 1024;
    i0 = (rem & 15) * 64; j0 = (rem >> 4) * 64;
  } else {
    const int rem = bid - 2048;
    inp = W2; outp = W2T; istride = 1024; ostride = 4096;
    i0 = (rem >> 4) * 64; j0 = (rem & 15) * 64;
  }
  __shared__ bf16_t tile[64][65];
  const int r = threadIdx.x >> 2, cs = (threadIdx.x & 3) * 16;
#pragma unroll
  for (int jj = 0; jj < 16; jj++)
    tile[cs + jj][r] = (bf16_t)inp[(long)(i0 + r) * istride + j0 + cs + jj];
  __syncthreads();
#pragma unroll
  for (int jj = 0; jj < 16; jj++)
    outp[(long)(j0 + r) * ostride + i0 + cs + jj] = tile[r][cs + jj];
}

// ---------------- LayerNorm (standalone, for post-Wo LN) ----------------
__global__ __launch_bounds__(256) void ln_kernel(const float* __restrict__ in,
                                                 const float* __restrict__ g,
                                                 const float* __restrict__ be,
                                                 bf16_t* __restrict__ out) {
  const int row = blockIdx.x, t = threadIdx.x;
  const float4 xv = ((const float4*)(in + (long)row * 1024))[t];
  float s1 = xv.x + xv.y + xv.z + xv.w;
  float s2 = xv.x * xv.x + xv.y * xv.y + xv.z * xv.z + xv.w * xv.w;
#pragma unroll
  for (int m = 1; m < 64; m <<= 1) {
    s1 += __shfl_xor(s1, m);
    s2 += __shfl_xor(s2, m);
  }
  __shared__ float r1[4], r2[4];
  if ((t & 63) == 0) { r1[t >> 6] = s1; r2[t >> 6] = s2; }
  __syncthreads();
  s1 = r1[0] + r1[1] + r1[2] + r1[3];
  s2 = r2[0] + r2[1] + r2[2] + r2[3];
  const float mean = s1 * (1.0f / 1024.0f);
  float var = s2 * (1.0f / 1024.0f) - mean * mean;
  const float rstd = rsqrtf(fmaxf(var, 0.0f) + 1e-5f);
  const float4 gv = ((const float4*)g)[t];
  const float4 bv = ((const float4*)be)[t];
  bf16x4 o;
  o[0] = (bf16_t)((xv.x - mean) * rstd * gv.x + bv.x);
  o[1] = (bf16_t)((xv.y - mean) * rstd * gv.y + bv.y);
  o[2] = (bf16_t)((xv.z - mean) * rstd * gv.z + bv.z);
  o[3] = (bf16_t)((xv.w - mean) * rstd * gv.w + bv.w);
  *(bf16x4*)(out + (long)row * 1024 + t * 4) = o;
}

// ---------------- W2 split-K reduce: out += sum(partials) + b2 ----------------
__global__ __launch_bounds__(256) void reduce_w2(const bf16_t* __restrict__ part,
                                                 const float* __restrict__ b2,
                                                 float* __restrict__ out) {
  const long base = (long)blockIdx.x * 1024 + threadIdx.x * 4;
  float4 o = *(float4*)(out + base);
  const float4 bb = ((const float4*)b2)[threadIdx.x];
  float s0 = 0.0f, s1 = 0.0f, s2 = 0.0f, s3 = 0.0f;
#pragma unroll
  for (int s = 0; s < 4; s++) {
    bf16x4 p = *(const bf16x4*)(part + ((long)s << 22) + base);
    s0 += (float)p[0];
    s1 += (float)p[1];
    s2 += (float)p[2];
    s3 += (float)p[3];
  }
  o.x += s0 + bb.x;
  o.y += s1 + bb.y;
  o.z += s2 + bb.z;
  o.w += s3 + bb.w;
  *(float4*)(out + base) = o;
}

// ====== gemm256: 256x256 tile, 8 waves, BK=64 as 2 kk-halves, 4 phases/K-tile ======
// EPI 2: gelu(bias)->bf16 (W1) ; EPI 7: split-K bf16 partials (W2)
template <int EPI, int RW>
__global__ __launch_bounds__(512, 2) void gemm256(const bf16_t* __restrict__ A,
                                                  const bf16_t* __restrict__ Bt,
                                                  const float* __restrict__ bias,
                                                  void* __restrict__ Cout,
                                                  int M, int N, int K) {
  __shared__ bf16_t a_l[2][2][256 * 32];
  __shared__ bf16_t b_l[2][2][256 * 32];
  const int tid = threadIdx.x, l = tid & 63, wid = tid >> 6;
  const int wr = wid >> 2, wc = wid & 3;
  const int lr = l & 15, lg = l >> 4;
  const int nwg = gridDim.x * gridDim.y * gridDim.z;
  const int orig = (blockIdx.z * gridDim.y + blockIdx.y) * gridDim.x + blockIdx.x;
  int bx, by, ks = 0;
  if (EPI == 7) {
    const int lid = (orig & 7) * (nwg >> 3) + (orig >> 3);
    bx = lid % gridDim.x;
    by = (lid / gridDim.x) % gridDim.y;
    ks = lid / (gridDim.x * gridDim.y);
  } else {
    const int cpx = nwg >> 3;
    const int xcd = orig & 7, ii = orig >> 3;
    const int rpr = gridDim.x / RW;
    bx = (xcd % rpr) * RW + (ii % RW);
    by = (xcd / rpr) * (cpx / RW) + (ii / RW);
  }
  const int m0 = by * 256, n0 = bx * 256;
  const long kbase = (EPI == 7) ? (long)ks << 10 : 0;
  const int nt = (EPI == 7) ? 16 : (K >> 6);
  const int sr0 = tid >> 2, sr1 = 128 + (tid >> 2);
  const int sch2 = ((tid & 3) ^ ((tid >> 3) & 3)) * 8;
  const int sl0 = sr0 * 32 + (tid & 3) * 8;
  const int sl1 = sr1 * 32 + (tid & 3) * 8;
#define STG_A(bufi, kki, kcol)                                                  \
  do {                                                                          \
    gload16(A + (long)(m0 + sr0) * K + (kcol) + sch2, &a_l[bufi][kki][sl0]);    \
    gload16(A + (long)(m0 + sr1) * K + (kcol) + sch2, &a_l[bufi][kki][sl1]);    \
  } while (0)
#define STG_B(bufi, kki, kcol)                                                  \
  do {                                                                          \
    gload16(Bt + (long)(n0 + sr0) * K + (kcol) + sch2, &b_l[bufi][kki][sl0]);   \
    gload16(Bt + (long)(n0 + sr1) * K + (kcol) + sch2, &b_l[bufi][kki][sl1]);   \
  } while (0)
  const int ch = (lg ^ ((lr >> 1) & 3)) * 8;
  f32x4 acc[8][4] = {};
  bf16x8 af[8], bf2[2];
  STG_A(0, 0, kbase + 0); STG_B(0, 0, kbase + 0);
  STG_A(0, 1, kbase + 32); STG_B(0, 1, kbase + 32);
  STG_A(1, 0, kbase + 64); STG_B(1, 0, kbase + 64);
  asm volatile("s_waitcnt vmcnt(8)" ::: "memory");
  __builtin_amdgcn_s_barrier();
  for (int t = 0; t < nt; t++) {
    const int buf = t & 1, nbuf = buf ^ 1;
    const long kc = kbase + (long)t * 64;
#define RD_A(kki)                                                      \
  _Pragma("unroll") for (int m = 0; m < 8; m++) af[m] =                \
      *(const bf16x8*)&a_l[buf][kki][(wr * 128 + m * 16 + lr) * 32 + ch];
#define RD_B(kki, nh)                                                  \
  _Pragma("unroll") for (int j = 0; j < 2; j++) bf2[j] =               \
      *(const bf16x8*)&b_l[buf][kki][(wc * 64 + ((nh)*2 + j) * 16 + lr) * 32 + ch];
#define MM(nh)                                                         \
  __builtin_amdgcn_s_setprio(1);                                       \
  _Pragma("unroll") for (int m = 0; m < 8; m++) {                      \
    acc[m][(nh)*2 + 0] = mfma16(af[m], bf2[0], acc[m][(nh)*2 + 0]);    \
    acc[m][(nh)*2 + 1] = mfma16(af[m], bf2[1], acc[m][(nh)*2 + 1]);    \
  }                                                                    \
  __builtin_amdgcn_s_setprio(0);
    RD_A(0); RD_B(0, 0);
    if (t + 1 < nt) { STG_A(nbuf, 1, kc + 96); }
    __builtin_amdgcn_s_barrier();
    asm volatile("s_waitcnt lgkmcnt(0)" ::: "memory");
    __builtin_amdgcn_sched_barrier(0);
    MM(0);
    __builtin_amdgcn_s_barrier();
    RD_B(0, 1);
    if (t + 1 < nt) { STG_B(nbuf, 1, kc + 96); }
    if (t + 1 < nt) asm volatile("s_waitcnt vmcnt(8)" ::: "memory");
    else            asm volatile("s_waitcnt vmcnt(0)" ::: "memory");
    __builtin_amdgcn_s_barrier();
    asm volatile("s_waitcnt lgkmcnt(0)" ::: "memory");
    __builtin_amdgcn_sched_barrier(0);
    MM(1);
    __builtin_amdgcn_s_barrier();
    RD_A(1); RD_B(1, 0);
    if (t + 2 < nt) { STG_A(buf, 0, kc + 128); }
    __builtin_amdgcn_s_barrier();
    asm volatile("s_waitcnt lgkmcnt(0)" ::: "memory");
    __builtin_amdgcn_sched_barrier(0);
    MM(0);
    __builtin_amdgcn_s_barrier();
    RD_B(1, 1);
    if (t + 2 < nt) { STG_B(buf, 0, kc + 128); }
    if (t + 2 < nt)      asm volatile("s_waitcnt vmcnt(8)" ::: "memory");
    else if (t + 1 < nt) asm volatile("s_waitcnt vmcnt(4)" ::: "memory");
    __builtin_amdgcn_s_barrier();
    asm volatile("s_waitcnt lgkmcnt(0)" ::: "memory");
    __builtin_amdgcn_sched_barrier(0);
    MM(1);
    __builtin_amdgcn_s_barrier();
  }
#undef RD_A
#undef RD_B
#undef MM
#undef STG_A
#undef STG_B
#pragma unroll
  for (int m = 0; m < 8; m++)
#pragma unroll
    for (int n = 0; n < 4; n++) {
      const int row_b = m0 + wr * 128 + m * 16 + lg * 4;
      const int col = n0 + wc * 64 + n * 16 + lr;
      if (EPI == 2) {
        const float bia = bias[col];
#pragma unroll
        for (int r = 0; r < 4; r++) {
          const long idx = (long)(row_b + r) * N + col;
          ((bf16_t*)Cout)[idx] = (bf16_t)gelu_f(acc[m][n][r] + bia);
        }
      } else if (EPI == 7) {
        bf16_t* part = (bf16_t*)Cout + ((long)ks << 22);
#pragma unroll
        for (int r = 0; r < 4; r++)
          part[(long)(row_b + r) * N + col] = (bf16_t)acc[m][n][r];
      }
    }
}

// ---------------- GEMM BK=32 (QKV): 3-buffer, counted vmcnt, 2D XCD regions ----------------
template <int EPI, int BN, int RW>
__global__ __launch_bounds__(256) void gemm32(const bf16_t* __restrict__ A,
                                              const bf16_t* __restrict__ A2,
                                              const bf16_t* __restrict__ Bt,
                                              const float* __restrict__ bias,
                                              const float* __restrict__ biasB,
                                              const float* __restrict__ biasC,
                                              bf16_t* __restrict__ aux,
                                              void* __restrict__ Cout,
                                              int M, int N, int K) {
  constexpr int NF = BN / 32;
  constexpr int NBI = BN / 64;
  __shared__ bf16_t a_lds[3][128 * 32];
  __shared__ bf16_t b_lds[3][BN * 32];
  const int tid = threadIdx.x, l = tid & 63, w = tid >> 6;
  const int wr = w >> 1, wc = w & 1;
  const int nwg = gridDim.x * gridDim.y;
  const int orig = blockIdx.y * gridDim.x + blockIdx.x;
  const int cpx = nwg >> 3;
  const int xcd = orig & 7, ii = orig >> 3;
  const int rpr = gridDim.x / RW;
  const int bx = (xcd % rpr) * RW + (ii % RW);
  const int by = (xcd / rpr) * (cpx / RW) + (ii / RW);
  const int m0 = by * 128, n0 = bx * BN;
  const bf16_t* Ause = (EPI == 5 && n0 >= 1024) ? A2 : A;
  const int lr = l & 15, lg = l >> 4;
  long a_src[2];
  int a_dst[2];
#pragma unroll
  for (int i = 0; i < 2; i++) {
    const int row = i * 64 + (tid >> 2);
    const int sc = ((tid & 3) ^ ((row >> 1) & 3)) * 8;
    a_src[i] = (long)(m0 + row) * K + sc;
    a_dst[i] = (i * 64 + w * 16) * 32;
  }
  long b_src[NBI];
#pragma unroll
  for (int i = 0; i < NBI; i++) {
    const int row = i * 64 + (tid >> 2);
    const int sc = ((tid & 3) ^ ((row >> 1) & 3)) * 8;
    b_src[i] = (long)(n0 + row) * K + sc;
  }
  const int nk = K >> 5;
  f32x4 acc[4][NF] = {};
#pragma unroll
  for (int tt = 0; tt < 2; tt++) {
#pragma unroll
    for (int i = 0; i < 2; i++) gload16(Ause + a_src[i] + tt * 32, &a_lds[tt][a_dst[i]]);
#pragma unroll
    for (int i = 0; i < NBI; i++) gload16(Bt + b_src[i] + tt * 32, &b_lds[tt][a_dst[i]]);
  }
  int cu = 0;
  for (int t = 0; t < nk; t++) {
    if (t + 1 < nk) asm volatile("s_waitcnt vmcnt(4)" ::: "memory");
    else            asm volatile("s_waitcnt vmcnt(0)" ::: "memory");
    __builtin_amdgcn_s_barrier();
    __builtin_amdgcn_sched_barrier(0);
    if (t + 2 < nk) {
      const long k0 = (long)(t + 2) * 32;
      const int nb = cu >= 1 ? cu - 1 : 2;
#pragma unroll
      for (int i = 0; i < 2; i++) gload16(Ause + a_src[i] + k0, &a_lds[nb][a_dst[i]]);
#pragma unroll
      for (int i = 0; i < NBI; i++) gload16(Bt + b_src[i] + k0, &b_lds[nb][a_dst[i]]);
    }
    const char* ab = (const char*)&a_lds[cu][0];
    const char* bb = (const char*)&b_lds[cu][0];
    bf16x8 af[4], bfr[NF];
#pragma unroll
    for (int m = 0; m < 4; m++) {
      const int row = wr * 64 + m * 16 + lr;
      af[m] = *(const bf16x8*)(ab + row * 64 + 16 * (lg ^ ((row >> 1) & 3)));
    }
#pragma unroll
    for (int n = 0; n < NF; n++) {
      const int row = wc * (BN / 2) + n * 16 + lr;
      bfr[n] = *(const bf16x8*)(bb + row * 64 + 16 * (lg ^ ((row >> 1) & 3)));
    }
    __builtin_amdgcn_s_setprio(1);
#pragma unroll
    for (int m = 0; m < 4; m++)
#pragma unroll
      for (int n = 0; n < NF; n++) acc[m][n] = mfma16(af[m], bfr[n], acc[m][n]);
    __builtin_amdgcn_s_setprio(0);
    cu = cu < 2 ? cu + 1 : 0;
  }
#pragma unroll
  for (int m = 0; m < 4; m++)
#pragma unroll
    for (int n = 0; n < NF; n++) {
      const int row_b = m0 + wr * 64 + m * 16 + (l >> 4) * 4;
      const int col = n0 + wc * (BN / 2) + n * 16 + lr;
      if (EPI == 5) {
        if (col < 1024) {
          const float bia = bias[col];
#pragma unroll
          for (int r = 0; r < 4; r++)
            ((bf16_t*)Cout)[hmi(row_b + r, col)] = (bf16_t)((acc[m][n][r] + bia) * QSCALE);
        } else if (col < 2048) {
          const float bia = biasB[col - 1024];
#pragma unroll
          for (int r = 0; r < 4; r++)
            ((bf16_t*)Cout + 4194304)[hmi(row_b + r, col - 1024)] =
                (bf16_t)(acc[m][n][r] + bia);
        } else {
          const int vcol = col - 2048;
          const float bia = biasC[vcol];
          bf16x4 vv;
#pragma unroll
          for (int r = 0; r < 4; r++) vv[r] = (bf16_t)(acc[m][n][r] + bia);
          const int bb2 = row_b >> 11, tt = row_b & 2047;
          *(bf16x4*)&aux[(((long)(bb2 << 4) + (vcol >> 6)) * 64 + (vcol & 63)) * 2048 + tt] = vv;
        }
      }
    }
}

// ---------------- GEMM BK=64 (Wo: BN=64, 48KB LDS): EPI 1 = bias+res -> fp32 ----------------
template <int EPI, int BN>
__global__ __launch_bounds__(256) void gemm64(const bf16_t* __restrict__ A,
                                              const bf16_t* __restrict__ Bt,
                                              const float* __restrict__ bias,
                                              const float* __restrict__ res,
                                              void* __restrict__ Cout,
                                              int M, int N, int K) {
  constexpr int NF = BN / 32;
  constexpr int NBI = BN / 32;
  __shared__ bf16_t a_lds[2][128 * 64];
  __shared__ bf16_t b_lds[2][BN * 64];
  const int tid = threadIdx.x, l = tid & 63, w = tid >> 6;
  const int wr = w >> 1, wc = w & 1;
  const int nwg = gridDim.x * gridDim.y;
  const int orig = blockIdx.y * gridDim.x + blockIdx.x;
  const int lid = (orig & 7) * (nwg >> 3) + (orig >> 3);
  const int bx = lid % gridDim.x, by = lid / gridDim.x;
  const int m0 = by * 128, n0 = bx * BN;
  const int lr = l & 15, lg = l >> 4;
  long a_src[4];
  int ldst[4];
#pragma unroll
  for (int i = 0; i < 4; i++) {
    const int row = i * 32 + w * 8 + (l >> 3);
    const int sc = ((l & 7) ^ (row & 7)) * 8;
    a_src[i] = (long)(m0 + row) * K + sc;
    ldst[i] = (i * 32 + w * 8) * 64;
  }
  long b_src[NBI];
#pragma unroll
  for (int i = 0; i < NBI; i++) {
    const int row = i * 32 + w * 8 + (l >> 3);
    const int sc = ((l & 7) ^ (row & 7)) * 8;
    b_src[i] = (long)(n0 + row) * K + sc;
  }
  const int nk = K >> 6;
  f32x4 acc[4][NF] = {};
#pragma unroll
  for (int i = 0; i < 4; i++) gload16(A + a_src[i], &a_lds[0][ldst[i]]);
#pragma unroll
  for (int i = 0; i < NBI; i++) gload16(Bt + b_src[i], &b_lds[0][ldst[i]]);
  __syncthreads();
  const int sw = (lr & 7) << 4;
  int cur = 0;
  for (int t = 0; t < nk; t++) {
    if (t + 1 < nk) {
      const long k0 = (long)(t + 1) * 64;
#pragma unroll
      for (int i = 0; i < 4; i++) gload16(A + a_src[i] + k0, &a_lds[cur ^ 1][ldst[i]]);
#pragma unroll
      for (int i = 0; i < NBI; i++) gload16(Bt + b_src[i] + k0, &b_lds[cur ^ 1][ldst[i]]);
    }
    const char* ab = (const char*)&a_lds[cur][0];
    const char* bb = (const char*)&b_lds[cur][0];
    bf16x8 af[4][2], bfr[NF][2];
#pragma unroll
    for (int m = 0; m < 4; m++) {
      const int rb = (wr * 64 + m * 16 + lr) * 128;
      af[m][0] = *(const bf16x8*)(ab + rb + ((16 * lg) ^ sw));
      af[m][1] = *(const bf16x8*)(ab + rb + ((16 * lg + 64) ^ sw));
    }
#pragma unroll
    for (int n = 0; n < NF; n++) {
      const int rb = (wc * (BN / 2) + n * 16 + lr) * 128;
      bfr[n][0] = *(const bf16x8*)(bb + rb + ((16 * lg) ^ sw));
      bfr[n][1] = *(const bf16x8*)(bb + rb + ((16 * lg + 64) ^ sw));
    }
    __builtin_amdgcn_s_setprio(1);
#pragma unroll
    for (int kk = 0; kk < 2; kk++)
#pragma unroll
      for (int m = 0; m < 4; m++)
#pragma unroll
        for (int n = 0; n < NF; n++)
          acc[m][n] = mfma16(af[m][kk], bfr[n][kk], acc[m][n]);
    __builtin_amdgcn_s_setprio(0);
    __syncthreads();
    cur ^= 1;
  }
#pragma unroll
  for (int m = 0; m < 4; m++)
#pragma unroll
    for (int n = 0; n < NF; n++) {
      const int row_b = m0 + wr * 64 + m * 16 + (l >> 4) * 4;
      const int col = n0 + wc * (BN / 2) + n * 16 + lr;
      const float bia = bias[col];
#pragma unroll
      for (int r = 0; r < 4; r++) {
        const long idx = (long)(row_b + r) * N + col;
        ((float*)Cout)[idx] = acc[m][n][r] + bia + res[idx];
      }
    }
}

// ---------------- fused attention v7: QBLK=128 (2 q-groups/wave) ----------------
__global__ __launch_bounds__(256) void attn_kernel(const bf16_t* __restrict__ qhm,
                                                   const bf16_t* __restrict__ khm,
                                                   const bf16_t* __restrict__ vtg,
                                                   bf16_t* __restrict__ og,
                                                   const int* __restrict__ maskp) {
  const int T = 2048, HP = 1024;
  __shared__ bf16_t k_lds[2][64 * 64];
  __shared__ bf16_t vt_lds[2][64 * 64];
  __shared__ bf16_t p_lds[4 * 32 * 72];
  const int bh = blockIdx.x, b = bh >> 4, h = bh & 15;
  const int q0 = blockIdx.y * 128;
  const int tid = threadIdx.x, l = tid & 63, w = tid >> 6;
  const int lr = l & 15, lg = l >> 4, lg4 = lg * 4;
  const int srow0 = q0 + w * 32 + lr;
  const bf16_t* kbase = khm + (long)bh * T * 64;
  const bf16_t* vbase = vtg + (long)bh * 64 * T;
  bf16x8 qf[2][2];
#pragma unroll
  for (int g = 0; g < 2; g++) {
    const bf16_t* qr = qhm + ((long)bh * 2048 + srow0 + g * 16) * 64 + lg * 8;
    qf[g][0] = *(const bf16x8*)qr;
    qf[g][1] = *(const bf16x8*)(qr + 32);
  }
  bf16_t* pl = &p_lds[w * 32 * 72];
  float lpart[2] = {0.0f, 0.0f};
  f32x4 oat[4][2] = {};

  const int swz = (lr & 7) << 4;
  const int fo0 = lr * 128 + ((16 * lg) ^ swz);
  const int fo1 = lr * 128 + ((64 + 16 * lg) ^ swz);

  const bool do_mask = (maskp[0] != 0);
  const int nM = do_mask ? (q0 >> 6) : 0;
  const int nt = T >> 6;

  const int sch = l & 7, srow8 = l >> 3;
  int cur = 0;
  {
    const bool needV = (nM == 0);
#pragma unroll
    for (int i = 0; i < 2; i++) {
      const int row = (i * 4 + w) * 8 + srow8;
      const int sc = (sch ^ (row & 7)) * 8;
      gload16(kbase + (long)row * 64 + sc, &k_lds[0][(i * 4 + w) * 512]);
      if (needV) gload16(vbase + (long)row * 2048 + 0 + sc, &vt_lds[0][(i * 4 + w) * 512]);
    }
  }
  __syncthreads();

  for (int t = 0; t < nt; t++) {
    const int t0 = t << 6;
    const int mode = (t < nM) ? 0 : ((do_mask && t < nM + 2) ? 1 : 2);
    if (t + 1 < nt) {
      const int t1 = (t + 1) << 6;
      const bool needV = (t + 1) >= nM;
#pragma unroll
      for (int i = 0; i < 2; i++) {
        const int row = (i * 4 + w) * 8 + srow8;
        const int sc = (sch ^ (row & 7)) * 8;
        gload16(kbase + (long)(t1 + row) * 64 + sc, &k_lds[cur ^ 1][(i * 4 + w) * 512]);
        if (needV)
          gload16(vbase + (long)row * 2048 + t1 + sc, &vt_lds[cur ^ 1][(i * 4 + w) * 512]);
      }
    }
    const char* kb = (const char*)&k_lds[cur][0];
    f32x4 sacc[4][2];
    __builtin_amdgcn_s_setprio(1);
#pragma unroll
    for (int n = 0; n < 4; n++) {
      bf16x8 kf0 = *(const bf16x8*)(kb + n * 2048 + fo0);
      bf16x8 kf1 = *(const bf16x8*)(kb + n * 2048 + fo1);
#pragma unroll
      for (int g = 0; g < 2; g++) {
        f32x4 z = {0.0f, 0.0f, 0.0f, 0.0f};
        z = mfma16(kf0, qf[g][0], z);
        sacc[n][g] = mfma16(kf1, qf[g][1], z);
      }
    }
    __builtin_amdgcn_s_setprio(0);
    float pv[2][4][4];
#pragma unroll
    for (int g = 0; g < 2; g++) {
      float psn[4];
#pragma unroll
      for (int n = 0; n < 4; n++) {
        pv[g][n][0] = exp2_fast(sacc[n][g][0]);
        pv[g][n][1] = exp2_fast(sacc[n][g][1]);
        pv[g][n][2] = exp2_fast(sacc[n][g][2]);
        pv[g][n][3] = exp2_fast(sacc[n][g][3]);
        psn[n] = (pv[g][n][0] + pv[g][n][1]) + (pv[g][n][2] + pv[g][n][3]);
      }
      lpart[g] += (psn[0] + psn[1]) + (psn[2] + psn[3]);
    }
    if (mode > 0) {
#pragma unroll
      for (int g = 0; g < 2; g++)
#pragma unroll
        for (int n = 0; n < 4; n++) {
          bf16x4 pk;
#pragma unroll
          for (int r = 0; r < 4; r++) {
            float v = pv[g][n][r];
            if (mode == 1 && (t0 + n * 16 + lg4 + r) <= srow0 + g * 16) v = 0.0f;
            pk[r] = (bf16_t)v;
          }
          *(bf16x4*)&pl[(g * 16 + lr) * 72 + n * 16 + lg4] = pk;
        }
      const char* vtb = (const char*)&vt_lds[cur][0];
      __builtin_amdgcn_s_setprio(1);
#pragma unroll
      for (int kk = 0; kk < 2; kk++) {
        bf16x8 pb0 = *(bf16x8*)&pl[lr * 72 + kk * 32 + lg * 8];
        bf16x8 pb1 = *(bf16x8*)&pl[(16 + lr) * 72 + kk * 32 + lg * 8];
        const int fkk = lr * 128 + ((kk * 64 + 16 * lg) ^ swz);
#pragma unroll
        for (int np = 0; np < 4; np++) {
          bf16x8 vtf = *(const bf16x8*)(vtb + np * 2048 + fkk);
          oat[np][0] = mfma16(vtf, pb0, oat[np][0]);
          oat[np][1] = mfma16(vtf, pb1, oat[np][1]);
        }
      }
      __builtin_amdgcn_s_setprio(0);
    }
    __syncthreads();
    cur ^= 1;
  }
  float inv[2];
#pragma unroll
  for (int g = 0; g < 2; g++) {
    float lsum = lpart[g];
    lsum += __shfl_xor(lsum, 16);
    lsum += __shfl_xor(lsum, 32);
    inv[g] = 1.0f / lsum;
  }
#pragma unroll
  for (int g = 0; g < 2; g++)
#pragma unroll
    for (int np = 0; np < 4; np++) {
      bf16x4 o4;
#pragma unroll
      for (int r = 0; r < 4; r++) o4[r] = (bf16_t)(oat[np][g][r] * inv[g]);
      *(bf16x4*)&pl[(g * 16 + lr) * 72 + np * 16 + lg4] = o4;
    }
  const int es = l >> 2, ec = (l & 3) * 16;
#pragma unroll
  for (int g = 0; g < 2; g++) {
    bf16x8 o0 = *(bf16x8*)&pl[(g * 16 + es) * 72 + ec];
    bf16x8 o1 = *(bf16x8*)&pl[(g * 16 + es) * 72 + ec + 8];
    bf16_t* orow = og + (long)(b * 2048 + q0 + w * 32 + g * 16 + es) * HP + h * 64 + ec;
    *(bf16x8*)&orow[0] = o0;
    *(bf16x8*)&orow[8] = o1;
  }
}

extern "C" void kernel_launch(void* const* d_in, const int* in_sizes, int n_in,
                              void* d_out, int out_size, void* d_ws, size_t ws_size,
                              hipStream_t stream) {
  const float* x = (const float*)d_in[0];
  const float* y = (const float*)d_in[1];
  const float* gxg = (const float*)d_in[2];
  const float* gxb = (const float*)d_in[3];
  const float* gyg = (const float*)d_in[4];
  const float* gyb = (const float*)d_in[5];
  const float* Wq = (const float*)d_in[6];
  const float* bq = (const float*)d_in[7];
  const float* Wk = (const float*)d_in[8];
  const float* bk = (const float*)d_in[9];
  const float* Wv = (const float*)d_in[10];
  const float* bv = (const float*)d_in[11];
  const float* Wo = (const float*)d_in[12];
  const float* bo = (const float*)d_in[13];
  const float* gdg = (const float*)d_in[14];
  const float* gdb = (const float*)d_in[15];
  const float* W1 = (const float*)d_in[16];
  const float* b1 = (const float*)d_in[17];
  const float* W2 = (const float*)d_in[18];
  const float* b2 = (const float*)d_in[19];
  const int* maskp = (const int*)d_in[20];
  float* out = (float*)d_out;

  char* ws = (char*)d_ws;
  const long MB = 1024 * 1024;
  bf16_t* xn = (bf16_t*)(ws + 0);
  bf16_t* yn = (bf16_t*)(ws + 8 * MB);
  bf16_t* WqkvT = (bf16_t*)(ws + 16 * MB);
  bf16_t* WoT = (bf16_t*)(ws + 22 * MB);
  bf16_t* W1T = (bf16_t*)(ws + 24 * MB);
  bf16_t* W2T = (bf16_t*)(ws + 32 * MB);
  bf16_t* qhm = (bf16_t*)(ws + 40 * MB);
  bf16_t* vTb = (bf16_t*)(ws + 64 * MB);
  bf16_t* ob = (bf16_t*)(ws + 0);
  bf16_t* xd = (bf16_t*)(ws + 8 * MB);
  bf16_t* hb = (bf16_t*)(ws + 40 * MB);
  bf16_t* w2part = (bf16_t*)(ws + 0);  // [4][4096][1024] bf16 = 32MB; xn/ob/xd dead by W2
  bf16_t* khm = qhm + 4194304;

  prep_all<<<11264, 256, 0, stream>>>(Wq, Wk, Wv, Wo, W1, W2, WqkvT, WoT, W1T, W2T, x, y, gxg,
                                      gxb, gyg, gyb, xn, yn);
  gemm32<5, 128, 12><<<dim3(24, 32), 256, 0, stream>>>(xn, yn, WqkvT, bq, bk, bv, vTb, qhm,
                                                       4096, 3072, 1024);
  attn_kernel<<<dim3(32, 16), 256, 0, stream>>>(qhm, khm, vTb, ob, maskp);
  gemm64<1, 64><<<dim3(16, 32), 256, 0, stream>>>(ob, WoT, bo, x, out, 4096, 1024, 1024);
  ln_kernel<<<4096, 256, 0, stream>>>(out, gdg, gdb, xd);
  gemm256<2, 4><<<dim3(16, 16), 512, 0, stream>>>(xd, W1T, b1, hb, 4096, 4096, 1024);
  gemm256<7, 4><<<dim3(4, 16, 4), 512, 0, stream>>>(hb, W2T, nullptr, w2part, 4096, 1024, 4096);
  reduce_w2<<<4096, 256, 0, stream>>>(w2part, b2, out);
}

// Round 19
// 220.658 us; speedup vs baseline: 1.0580x; 1.0172x over previous
//
#include <hip/hip_runtime.h>
#include <hip/hip_bf16.h>
#include <math.h>

// B=2, SX=SY=2048, XD=YD=1024, P=64, H=16, MULT=4
typedef __bf16 bf16_t;
typedef __bf16 bf16x8 __attribute__((ext_vector_type(8)));
typedef __bf16 bf16x4 __attribute__((ext_vector_type(4)));
typedef float f32x4 __attribute__((ext_vector_type(4)));

#define QSCALE 0.18033688011112042f /* 0.125 * log2(e): scores in log2 units */

static __device__ __forceinline__ f32x4 mfma16(bf16x8 a, bf16x8 b, f32x4 c) {
  return __builtin_amdgcn_mfma_f32_16x16x32_bf16(a, b, c, 0, 0, 0);
}

static __device__ __forceinline__ float exp2_fast(float x) {
  float r;
  asm("v_exp_f32 %0, %1" : "=v"(r) : "v"(x));
  return r;
}

// tanh-form GELU: 0.5x(1+tanh(u)) = x*e/(e+1), e = exp(2u), u = c1*x + c2*x^3.
static __device__ __forceinline__ float gelu_f(float x) {
  const float u = x * (0.7978845608028654f + 0.03567740813636141f * x * x);
  const float a = fminf(u * 2.885390081777927f, 126.0f);
  const float e = exp2_fast(a);
  float r;
  asm("v_rcp_f32 %0, %1" : "=v"(r) : "v"(e + 1.0f));
  return x * e * r;
}

typedef __attribute__((address_space(1))) const void as1_void;
typedef __attribute__((address_space(3))) void as3_void;
static __device__ __forceinline__ void gload16(const void* g, void* s) {
  __builtin_amdgcn_global_load_lds((as1_void*)g, (as3_void*)s, 16, 0, 0);
}

// head-major index: [b][h][s][p] from (row = b*2048+s, col = h*64+p)
static __device__ __forceinline__ long hmi(int row, int col) {
  return ((((long)(row >> 11) * 16 + (col >> 6)) * 2048) + (row & 2047)) * 64 + (col & 63);
}

// -------- merged prep: 6 weight transposes + both input LayerNorms, one launch --------
__global__ __launch_bounds__(256) void prep_all(
    const float* __restrict__ Wq, const float* __restrict__ Wk, const float* __restrict__ Wv,
    const float* __restrict__ Wo, const float* __restrict__ W1, const float* __restrict__ W2,
    bf16_t* __restrict__ WqkvT, bf16_t* __restrict__ WoT, bf16_t* __restrict__ W1T,
    bf16_t* __restrict__ W2T, const float* __restrict__ x, const float* __restrict__ y,
    const float* __restrict__ gx, const float* __restrict__ bex, const float* __restrict__ gy,
    const float* __restrict__ bey, bf16_t* __restrict__ xn, bf16_t* __restrict__ yn) {
  const int bid = blockIdx.x;
  if (bid >= 3072) {
    const int lrow = bid - 3072;
    const float* in = lrow < 4096 ? x : y;
    const float* g = lrow < 4096 ? gx : gy;
    const float* be = lrow < 4096 ? bex : bey;
    bf16_t* out = lrow < 4096 ? xn : yn;
    const int row = lrow & 4095;
    const int t = threadIdx.x;
    const float4 xv = ((const float4*)(in + (long)row * 1024))[t];
    float s1 = xv.x + xv.y + xv.z + xv.w;
    float s2 = xv.x * xv.x + xv.y * xv.y + xv.z * xv.z + xv.w * xv.w;
#pragma unroll
    for (int m = 1; m < 64; m <<= 1) {
      s1 += __shfl_xor(s1, m);
      s2 += __shfl_xor(s2, m);
    }
    __shared__ float r1[4], r2[4];
    if ((t & 63) == 0) { r1[t >> 6] = s1; r2[t >> 6] = s2; }
    __syncthreads();
    s1 = r1[0] + r1[1] + r1[2] + r1[3];
    s2 = r2[0] + r2[1] + r2[2] + r2[3];
    const float mean = s1 * (1.0f / 1024.0f);
    float var = s2 * (1.0f / 1024.0f) - mean * mean;
    const float rstd = rsqrtf(fmaxf(var, 0.0f) + 1e-5f);
    const float4 gv = ((const float4*)g)[t];
    const float4 bv = ((const float4*)be)[t];
    bf16x4 o;
    o[0] = (bf16_t)((xv.x - mean) * rstd * gv.x + bv.x);
    o[1] = (bf16_t)((xv.y - mean) * rstd * gv.y + bv.y);
    o[2] = (bf16_t)((xv.z - mean) * rstd * gv.z + bv.z);
    o[3] = (bf16_t)((xv.w - mean) * rstd * gv.w + bv.w);
    *(bf16x4*)(out + (long)row * 1024 + t * 4) = o;
    return;
  }
  const float* inp;
  bf16_t* outp;
  int istride, ostride, i0, j0;
  if (bid < 768) {
    const int wsel = bid >> 8, rem = bid & 255;
    const int h = rem >> 4, xt = rem & 15;
    const float* W = wsel == 0 ? Wq : (wsel == 1 ? Wk : Wv);
    inp = W + h * 65536;
    outp = WqkvT + (long)wsel * 1048576 + h * 65536;
    istride = 64; ostride = 1024; i0 = xt * 64; j0 = 0;
  } else if (bid < 1024) {
    const int rem = bid - 768;
    inp = Wo; outp = WoT; istride = 1024; ostride = 1024;
    i0 = (rem & 15) * 64; j0 = (rem >> 4) * 64;
  } else if (bid < 2048) {
    const int rem = bid - 1024;
    inp = W1; outp = W1T; istride = 4096; ostride = 1024;
    i0 = (rem & 15) * 64; j0 = (rem >> 4) * 64;
  } else {
    const int rem = bid - 2048;
    inp = W2; outp = W2T; istride = 1024; ostride = 4096;
    i0 = (rem >> 4) * 64; j0 = (rem & 15) * 64;
  }
  __shared__ bf16_t tile[64][65];
  const int r = threadIdx.x >> 2, cs = (threadIdx.x & 3) * 16;
#pragma unroll
  for (int jj = 0; jj < 16; jj++)
    tile[cs + jj][r] = (bf16_t)inp[(long)(i0 + r) * istride + j0 + cs + jj];
  __syncthreads();
#pragma unroll
  for (int jj = 0; jj < 16; jj++)
    outp[(long)(j0 + r) * ostride + i0 + cs + jj] = tile[r][cs + jj];
}

// ---------------- LayerNorm (standalone, for post-Wo LN) ----------------
__global__ __launch_bounds__(256) void ln_kernel(const float* __restrict__ in,
                                                 const float* __restrict__ g,
                                                 const float* __restrict__ be,
                                                 bf16_t* __restrict__ out) {
  const int row = blockIdx.x, t = threadIdx.x;
  const float4 xv = ((const float4*)(in + (long)row * 1024))[t];
  float s1 = xv.x + xv.y + xv.z + xv.w;
  float s2 = xv.x * xv.x + xv.y * xv.y + xv.z * xv.z + xv.w * xv.w;
#pragma unroll
  for (int m = 1; m < 64; m <<= 1) {
    s1 += __shfl_xor(s1, m);
    s2 += __shfl_xor(s2, m);
  }
  __shared__ float r1[4], r2[4];
  if ((t & 63) == 0) { r1[t >> 6] = s1; r2[t >> 6] = s2; }
  __syncthreads();
  s1 = r1[0] + r1[1] + r1[2] + r1[3];
  s2 = r2[0] + r2[1] + r2[2] + r2[3];
  const float mean = s1 * (1.0f / 1024.0f);
  float var = s2 * (1.0f / 1024.0f) - mean * mean;
  const float rstd = rsqrtf(fmaxf(var, 0.0f) + 1e-5f);
  const float4 gv = ((const float4*)g)[t];
  const float4 bv = ((const float4*)be)[t];
  bf16x4 o;
  o[0] = (bf16_t)((xv.x - mean) * rstd * gv.x + bv.x);
  o[1] = (bf16_t)((xv.y - mean) * rstd * gv.y + bv.y);
  o[2] = (bf16_t)((xv.z - mean) * rstd * gv.z + bv.z);
  o[3] = (bf16_t)((xv.w - mean) * rstd * gv.w + bv.w);
  *(bf16x4*)(out + (long)row * 1024 + t * 4) = o;
}

// ---------------- W2 split-K reduce: out += sum(partials) + b2 ----------------
__global__ __launch_bounds__(256) void reduce_w2(const bf16_t* __restrict__ part,
                                                 const float* __restrict__ b2,
                                                 float* __restrict__ out) {
  const long base = (long)blockIdx.x * 1024 + threadIdx.x * 4;
  float4 o = *(float4*)(out + base);
  const float4 bb = ((const float4*)b2)[threadIdx.x];
  float s0 = 0.0f, s1 = 0.0f, s2 = 0.0f, s3 = 0.0f;
#pragma unroll
  for (int s = 0; s < 4; s++) {
    bf16x4 p = *(const bf16x4*)(part + ((long)s << 22) + base);
    s0 += (float)p[0];
    s1 += (float)p[1];
    s2 += (float)p[2];
    s3 += (float)p[3];
  }
  o.x += s0 + bb.x;
  o.y += s1 + bb.y;
  o.z += s2 + bb.z;
  o.w += s3 + bb.w;
  *(float4*)(out + base) = o;
}

// ====== gemm256: 256x256 tile, 8 waves, BK=64 as 2 kk-halves, 4 phases/K-tile ======
// EPI 2: gelu(bias)->bf16 (W1) ; EPI 7: split-K bf16 partials (W2)
template <int EPI, int RW>
__global__ __launch_bounds__(512, 2) void gemm256(const bf16_t* __restrict__ A,
                                                  const bf16_t* __restrict__ Bt,
                                                  const float* __restrict__ bias,
                                                  void* __restrict__ Cout,
                                                  int M, int N, int K) {
  __shared__ bf16_t a_l[2][2][256 * 32];
  __shared__ bf16_t b_l[2][2][256 * 32];
  const int tid = threadIdx.x, l = tid & 63, wid = tid >> 6;
  const int wr = wid >> 2, wc = wid & 3;
  const int lr = l & 15, lg = l >> 4;
  const int nwg = gridDim.x * gridDim.y * gridDim.z;
  const int orig = (blockIdx.z * gridDim.y + blockIdx.y) * gridDim.x + blockIdx.x;
  int bx, by, ks = 0;
  if (EPI == 7) {
    const int lid = (orig & 7) * (nwg >> 3) + (orig >> 3);
    bx = lid % gridDim.x;
    by = (lid / gridDim.x) % gridDim.y;
    ks = lid / (gridDim.x * gridDim.y);
  } else {
    const int cpx = nwg >> 3;
    const int xcd = orig & 7, ii = orig >> 3;
    const int rpr = gridDim.x / RW;
    bx = (xcd % rpr) * RW + (ii % RW);
    by = (xcd / rpr) * (cpx / RW) + (ii / RW);
  }
  const int m0 = by * 256, n0 = bx * 256;
  const long kbase = (EPI == 7) ? (long)ks << 10 : 0;
  const int nt = (EPI == 7) ? 16 : (K >> 6);
  const int sr0 = tid >> 2, sr1 = 128 + (tid >> 2);
  const int sch2 = ((tid & 3) ^ ((tid >> 3) & 3)) * 8;
  const int sl0 = sr0 * 32 + (tid & 3) * 8;
  const int sl1 = sr1 * 32 + (tid & 3) * 8;
#define STG_A(bufi, kki, kcol)                                                  \
  do {                                                                          \
    gload16(A + (long)(m0 + sr0) * K + (kcol) + sch2, &a_l[bufi][kki][sl0]);    \
    gload16(A + (long)(m0 + sr1) * K + (kcol) + sch2, &a_l[bufi][kki][sl1]);    \
  } while (0)
#define STG_B(bufi, kki, kcol)                                                  \
  do {                                                                          \
    gload16(Bt + (long)(n0 + sr0) * K + (kcol) + sch2, &b_l[bufi][kki][sl0]);   \
    gload16(Bt + (long)(n0 + sr1) * K + (kcol) + sch2, &b_l[bufi][kki][sl1]);   \
  } while (0)
  const int ch = (lg ^ ((lr >> 1) & 3)) * 8;
  f32x4 acc[8][4] = {};
  bf16x8 af[8], bf2[2];
  STG_A(0, 0, kbase + 0); STG_B(0, 0, kbase + 0);
  STG_A(0, 1, kbase + 32); STG_B(0, 1, kbase + 32);
  STG_A(1, 0, kbase + 64); STG_B(1, 0, kbase + 64);
  asm volatile("s_waitcnt vmcnt(8)" ::: "memory");
  __builtin_amdgcn_s_barrier();
  for (int t = 0; t < nt; t++) {
    const int buf = t & 1, nbuf = buf ^ 1;
    const long kc = kbase + (long)t * 64;
#define RD_A(kki)                                                      \
  _Pragma("unroll") for (int m = 0; m < 8; m++) af[m] =                \
      *(const bf16x8*)&a_l[buf][kki][(wr * 128 + m * 16 + lr) * 32 + ch];
#define RD_B(kki, nh)                                                  \
  _Pragma("unroll") for (int j = 0; j < 2; j++) bf2[j] =               \
      *(const bf16x8*)&b_l[buf][kki][(wc * 64 + ((nh)*2 + j) * 16 + lr) * 32 + ch];
#define MM(nh)                                                         \
  __builtin_amdgcn_s_setprio(1);                                       \
  _Pragma("unroll") for (int m = 0; m < 8; m++) {                      \
    acc[m][(nh)*2 + 0] = mfma16(af[m], bf2[0], acc[m][(nh)*2 + 0]);    \
    acc[m][(nh)*2 + 1] = mfma16(af[m], bf2[1], acc[m][(nh)*2 + 1]);    \
  }                                                                    \
  __builtin_amdgcn_s_setprio(0);
    RD_A(0); RD_B(0, 0);
    if (t + 1 < nt) { STG_A(nbuf, 1, kc + 96); }
    __builtin_amdgcn_s_barrier();
    asm volatile("s_waitcnt lgkmcnt(0)" ::: "memory");
    __builtin_amdgcn_sched_barrier(0);
    MM(0);
    __builtin_amdgcn_s_barrier();
    RD_B(0, 1);
    if (t + 1 < nt) { STG_B(nbuf, 1, kc + 96); }
    if (t + 1 < nt) asm volatile("s_waitcnt vmcnt(8)" ::: "memory");
    else            asm volatile("s_waitcnt vmcnt(0)" ::: "memory");
    __builtin_amdgcn_s_barrier();
    asm volatile("s_waitcnt lgkmcnt(0)" ::: "memory");
    __builtin_amdgcn_sched_barrier(0);
    MM(1);
    __builtin_amdgcn_s_barrier();
    RD_A(1); RD_B(1, 0);
    if (t + 2 < nt) { STG_A(buf, 0, kc + 128); }
    __builtin_amdgcn_s_barrier();
    asm volatile("s_waitcnt lgkmcnt(0)" ::: "memory");
    __builtin_amdgcn_sched_barrier(0);
    MM(0);
    __builtin_amdgcn_s_barrier();
    RD_B(1, 1);
    if (t + 2 < nt) { STG_B(buf, 0, kc + 128); }
    if (t + 2 < nt)      asm volatile("s_waitcnt vmcnt(8)" ::: "memory");
    else if (t + 1 < nt) asm volatile("s_waitcnt vmcnt(4)" ::: "memory");
    __builtin_amdgcn_s_barrier();
    asm volatile("s_waitcnt lgkmcnt(0)" ::: "memory");
    __builtin_amdgcn_sched_barrier(0);
    MM(1);
    __builtin_amdgcn_s_barrier();
  }
#undef RD_A
#undef RD_B
#undef MM
#undef STG_A
#undef STG_B
#pragma unroll
  for (int m = 0; m < 8; m++)
#pragma unroll
    for (int n = 0; n < 4; n++) {
      const int row_b = m0 + wr * 128 + m * 16 + lg * 4;
      const int col = n0 + wc * 64 + n * 16 + lr;
      if (EPI == 2) {
        const float bia = bias[col];
#pragma unroll
        for (int r = 0; r < 4; r++) {
          const long idx = (long)(row_b + r) * N + col;
          ((bf16_t*)Cout)[idx] = (bf16_t)gelu_f(acc[m][n][r] + bia);
        }
      } else if (EPI == 7) {
        bf16_t* part = (bf16_t*)Cout + ((long)ks << 22);
#pragma unroll
        for (int r = 0; r < 4; r++)
          part[(long)(row_b + r) * N + col] = (bf16_t)acc[m][n][r];
      }
    }
}

// ---------------- GEMM BK=32 (QKV): 3-buffer, counted vmcnt, 2D XCD regions ----------------
template <int EPI, int BN, int RW>
__global__ __launch_bounds__(256) void gemm32(const bf16_t* __restrict__ A,
                                              const bf16_t* __restrict__ A2,
                                              const bf16_t* __restrict__ Bt,
                                              const float* __restrict__ bias,
                                              const float* __restrict__ biasB,
                                              const float* __restrict__ biasC,
                                              bf16_t* __restrict__ aux,
                                              void* __restrict__ Cout,
                                              int M, int N, int K) {
  constexpr int NF = BN / 32;
  constexpr int NBI = BN / 64;
  __shared__ bf16_t a_lds[3][128 * 32];
  __shared__ bf16_t b_lds[3][BN * 32];
  const int tid = threadIdx.x, l = tid & 63, w = tid >> 6;
  const int wr = w >> 1, wc = w & 1;
  const int nwg = gridDim.x * gridDim.y;
  const int orig = blockIdx.y * gridDim.x + blockIdx.x;
  const int cpx = nwg >> 3;
  const int xcd = orig & 7, ii = orig >> 3;
  const int rpr = gridDim.x / RW;
  const int bx = (xcd % rpr) * RW + (ii % RW);
  const int by = (xcd / rpr) * (cpx / RW) + (ii / RW);
  const int m0 = by * 128, n0 = bx * BN;
  const bf16_t* Ause = (EPI == 5 && n0 >= 1024) ? A2 : A;
  const int lr = l & 15, lg = l >> 4;
  long a_src[2];
  int a_dst[2];
#pragma unroll
  for (int i = 0; i < 2; i++) {
    const int row = i * 64 + (tid >> 2);
    const int sc = ((tid & 3) ^ ((row >> 1) & 3)) * 8;
    a_src[i] = (long)(m0 + row) * K + sc;
    a_dst[i] = (i * 64 + w * 16) * 32;
  }
  long b_src[NBI];
#pragma unroll
  for (int i = 0; i < NBI; i++) {
    const int row = i * 64 + (tid >> 2);
    const int sc = ((tid & 3) ^ ((row >> 1) & 3)) * 8;
    b_src[i] = (long)(n0 + row) * K + sc;
  }
  const int nk = K >> 5;
  f32x4 acc[4][NF] = {};
#pragma unroll
  for (int tt = 0; tt < 2; tt++) {
#pragma unroll
    for (int i = 0; i < 2; i++) gload16(Ause + a_src[i] + tt * 32, &a_lds[tt][a_dst[i]]);
#pragma unroll
    for (int i = 0; i < NBI; i++) gload16(Bt + b_src[i] + tt * 32, &b_lds[tt][a_dst[i]]);
  }
  int cu = 0;
  for (int t = 0; t < nk; t++) {
    if (t + 1 < nk) asm volatile("s_waitcnt vmcnt(4)" ::: "memory");
    else            asm volatile("s_waitcnt vmcnt(0)" ::: "memory");
    __builtin_amdgcn_s_barrier();
    __builtin_amdgcn_sched_barrier(0);
    if (t + 2 < nk) {
      const long k0 = (long)(t + 2) * 32;
      const int nb = cu >= 1 ? cu - 1 : 2;
#pragma unroll
      for (int i = 0; i < 2; i++) gload16(Ause + a_src[i] + k0, &a_lds[nb][a_dst[i]]);
#pragma unroll
      for (int i = 0; i < NBI; i++) gload16(Bt + b_src[i] + k0, &b_lds[nb][a_dst[i]]);
    }
    const char* ab = (const char*)&a_lds[cu][0];
    const char* bb = (const char*)&b_lds[cu][0];
    bf16x8 af[4], bfr[NF];
#pragma unroll
    for (int m = 0; m < 4; m++) {
      const int row = wr * 64 + m * 16 + lr;
      af[m] = *(const bf16x8*)(ab + row * 64 + 16 * (lg ^ ((row >> 1) & 3)));
    }
#pragma unroll
    for (int n = 0; n < NF; n++) {
      const int row = wc * (BN / 2) + n * 16 + lr;
      bfr[n] = *(const bf16x8*)(bb + row * 64 + 16 * (lg ^ ((row >> 1) & 3)));
    }
    __builtin_amdgcn_s_setprio(1);
#pragma unroll
    for (int m = 0; m < 4; m++)
#pragma unroll
      for (int n = 0; n < NF; n++) acc[m][n] = mfma16(af[m], bfr[n], acc[m][n]);
    __builtin_amdgcn_s_setprio(0);
    cu = cu < 2 ? cu + 1 : 0;
  }
#pragma unroll
  for (int m = 0; m < 4; m++)
#pragma unroll
    for (int n = 0; n < NF; n++) {
      const int row_b = m0 + wr * 64 + m * 16 + (l >> 4) * 4;
      const int col = n0 + wc * (BN / 2) + n * 16 + lr;
      if (EPI == 5) {
        if (col < 1024) {
          const float bia = bias[col];
#pragma unroll
          for (int r = 0; r < 4; r++)
            ((bf16_t*)Cout)[hmi(row_b + r, col)] = (bf16_t)((acc[m][n][r] + bia) * QSCALE);
        } else if (col < 2048) {
          const float bia = biasB[col - 1024];
#pragma unroll
          for (int r = 0; r < 4; r++)
            ((bf16_t*)Cout + 4194304)[hmi(row_b + r, col - 1024)] =
                (bf16_t)(acc[m][n][r] + bia);
        } else {
          const int vcol = col - 2048;
          const float bia = biasC[vcol];
          bf16x4 vv;
#pragma unroll
          for (int r = 0; r < 4; r++) vv[r] = (bf16_t)(acc[m][n][r] + bia);
          const int bb2 = row_b >> 11, tt = row_b & 2047;
          *(bf16x4*)&aux[(((long)(bb2 << 4) + (vcol >> 6)) * 64 + (vcol & 63)) * 2048 + tt] = vv;
        }
      }
    }
}

// ---------------- GEMM BK=64 (Wo: BN=64, 48KB LDS): EPI 1 = bias+res -> fp32 ----------------
template <int EPI, int BN>
__global__ __launch_bounds__(256) void gemm64(const bf16_t* __restrict__ A,
                                              const bf16_t* __restrict__ Bt,
                                              const float* __restrict__ bias,
                                              const float* __restrict__ res,
                                              void* __restrict__ Cout,
                                              int M, int N, int K) {
  constexpr int NF = BN / 32;
  constexpr int NBI = BN / 32;
  __shared__ bf16_t a_lds[2][128 * 64];
  __shared__ bf16_t b_lds[2][BN * 64];
  const int tid = threadIdx.x, l = tid & 63, w = tid >> 6;
  const int wr = w >> 1, wc = w & 1;
  const int nwg = gridDim.x * gridDim.y;
  const int orig = blockIdx.y * gridDim.x + blockIdx.x;
  const int lid = (orig & 7) * (nwg >> 3) + (orig >> 3);
  const int bx = lid % gridDim.x, by = lid / gridDim.x;
  const int m0 = by * 128, n0 = bx * BN;
  const int lr = l & 15, lg = l >> 4;
  long a_src[4];
  int ldst[4];
#pragma unroll
  for (int i = 0; i < 4; i++) {
    const int row = i * 32 + w * 8 + (l >> 3);
    const int sc = ((l & 7) ^ (row & 7)) * 8;
    a_src[i] = (long)(m0 + row) * K + sc;
    ldst[i] = (i * 32 + w * 8) * 64;
  }
  long b_src[NBI];
#pragma unroll
  for (int i = 0; i < NBI; i++) {
    const int row = i * 32 + w * 8 + (l >> 3);
    const int sc = ((l & 7) ^ (row & 7)) * 8;
    b_src[i] = (long)(n0 + row) * K + sc;
  }
  const int nk = K >> 6;
  f32x4 acc[4][NF] = {};
#pragma unroll
  for (int i = 0; i < 4; i++) gload16(A + a_src[i], &a_lds[0][ldst[i]]);
#pragma unroll
  for (int i = 0; i < NBI; i++) gload16(Bt + b_src[i], &b_lds[0][ldst[i]]);
  __syncthreads();
  const int sw = (lr & 7) << 4;
  int cur = 0;
  for (int t = 0; t < nk; t++) {
    if (t + 1 < nk) {
      const long k0 = (long)(t + 1) * 64;
#pragma unroll
      for (int i = 0; i < 4; i++) gload16(A + a_src[i] + k0, &a_lds[cur ^ 1][ldst[i]]);
#pragma unroll
      for (int i = 0; i < NBI; i++) gload16(Bt + b_src[i] + k0, &b_lds[cur ^ 1][ldst[i]]);
    }
    const char* ab = (const char*)&a_lds[cur][0];
    const char* bb = (const char*)&b_lds[cur][0];
    bf16x8 af[4][2], bfr[NF][2];
#pragma unroll
    for (int m = 0; m < 4; m++) {
      const int rb = (wr * 64 + m * 16 + lr) * 128;
      af[m][0] = *(const bf16x8*)(ab + rb + ((16 * lg) ^ sw));
      af[m][1] = *(const bf16x8*)(ab + rb + ((16 * lg + 64) ^ sw));
    }
#pragma unroll
    for (int n = 0; n < NF; n++) {
      const int rb = (wc * (BN / 2) + n * 16 + lr) * 128;
      bfr[n][0] = *(const bf16x8*)(bb + rb + ((16 * lg) ^ sw));
      bfr[n][1] = *(const bf16x8*)(bb + rb + ((16 * lg + 64) ^ sw));
    }
    __builtin_amdgcn_s_setprio(1);
#pragma unroll
    for (int kk = 0; kk < 2; kk++)
#pragma unroll
      for (int m = 0; m < 4; m++)
#pragma unroll
        for (int n = 0; n < NF; n++)
          acc[m][n] = mfma16(af[m][kk], bfr[n][kk], acc[m][n]);
    __builtin_amdgcn_s_setprio(0);
    __syncthreads();
    cur ^= 1;
  }
#pragma unroll
  for (int m = 0; m < 4; m++)
#pragma unroll
    for (int n = 0; n < NF; n++) {
      const int row_b = m0 + wr * 64 + m * 16 + (l >> 4) * 4;
      const int col = n0 + wc * (BN / 2) + n * 16 + lr;
      const float bia = bias[col];
#pragma unroll
      for (int r = 0; r < 4; r++) {
        const long idx = (long)(row_b + r) * N + col;
        ((float*)Cout)[idx] = acc[m][n][r] + bia + res[idx];
      }
    }
}

// ---------------- fused attention v9: QBLK=128, 8 waves (512 thr), 16 rows/wave --------
// Doubles resident waves/SIMD (2->4) for VALU/MFMA overlap; within-block waves
// co-schedule by construction (r17's extra-blocks approach did not).
__global__ __launch_bounds__(512) void attn_kernel(const bf16_t* __restrict__ qhm,
                                                   const bf16_t* __restrict__ khm,
                                                   const bf16_t* __restrict__ vtg,
                                                   bf16_t* __restrict__ og,
                                                   const int* __restrict__ maskp) {
  const int T = 2048, HP = 1024;
  __shared__ bf16_t k_lds[2][64 * 64];
  __shared__ bf16_t vt_lds[2][64 * 64];
  __shared__ bf16_t p_lds[8 * 16 * 72];
  const int bh = blockIdx.x, b = bh >> 4, h = bh & 15;
  const int q0 = blockIdx.y * 128;
  const int tid = threadIdx.x, l = tid & 63, w = tid >> 6;  // w in [0,8)
  const int lr = l & 15, lg = l >> 4, lg4 = lg * 4;
  const int srow = q0 + w * 16 + lr;  // this wave owns q-rows [q0+w*16, +16)
  const bf16_t* kbase = khm + (long)bh * T * 64;
  const bf16_t* vbase = vtg + (long)bh * 64 * T;
  const bf16_t* qr = qhm + ((long)bh * 2048 + srow) * 64 + lg * 8;
  bf16x8 qf0 = *(const bf16x8*)qr;
  bf16x8 qf1 = *(const bf16x8*)(qr + 32);
  bf16_t* pl = &p_lds[w * 16 * 72];
  float lpart = 0.0f;
  f32x4 oat[4] = {};

  const int swz = (lr & 7) << 4;
  const int fo0 = lr * 128 + ((16 * lg) ^ swz);
  const int fo1 = lr * 128 + ((64 + 16 * lg) ^ swz);

  const bool do_mask = (maskp[0] != 0);
  const int nM = do_mask ? (q0 >> 6) : 0;
  const int nt = T >> 6;

  // staging: wave w stages rows [w*8, w*8+8); lane l -> row w*8+(l>>3), chunk l&7,
  // inverse-swizzled source chunk ((l&7)^(l>>3))*8; linear LDS dest w*512 elems.
  const int srow8 = l >> 3, sch = l & 7;
  const int ssc = (sch ^ srow8) * 8;
  const int srw = w * 8 + srow8;
  int cur = 0;
  {
    const bool needV = (nM == 0);
    gload16(kbase + (long)srw * 64 + ssc, &k_lds[0][w * 512]);
    if (needV) gload16(vbase + (long)srw * 2048 + 0 + ssc, &vt_lds[0][w * 512]);
  }
  __syncthreads();

  for (int t = 0; t < nt; t++) {
    const int t0 = t << 6;
    const int mode = (t < nM) ? 0 : ((do_mask && t < nM + 2) ? 1 : 2);
    if (t + 1 < nt) {
      const int t1 = (t + 1) << 6;
      const bool needV = (t + 1) >= nM;
      gload16(kbase + (long)(t1 + srw) * 64 + ssc, &k_lds[cur ^ 1][w * 512]);
      if (needV) gload16(vbase + (long)srw * 2048 + t1 + ssc, &vt_lds[cur ^ 1][w * 512]);
    }
    const char* kb = (const char*)&k_lds[cur][0];
    f32x4 sacc[4];
    __builtin_amdgcn_s_setprio(1);
#pragma unroll
    for (int n = 0; n < 4; n++) {
      bf16x8 kf0 = *(const bf16x8*)(kb + n * 2048 + fo0);
      bf16x8 kf1 = *(const bf16x8*)(kb + n * 2048 + fo1);
      f32x4 z = {0.0f, 0.0f, 0.0f, 0.0f};
      z = mfma16(kf0, qf0, z);
      sacc[n] = mfma16(kf1, qf1, z);
    }
    __builtin_amdgcn_s_setprio(0);
    float pv[4][4], psn[4];
#pragma unroll
    for (int n = 0; n < 4; n++) {
      pv[n][0] = exp2_fast(sacc[n][0]);
      pv[n][1] = exp2_fast(sacc[n][1]);
      pv[n][2] = exp2_fast(sacc[n][2]);
      pv[n][3] = exp2_fast(sacc[n][3]);
      psn[n] = (pv[n][0] + pv[n][1]) + (pv[n][2] + pv[n][3]);
    }
    lpart += (psn[0] + psn[1]) + (psn[2] + psn[3]);
    if (mode > 0) {
#pragma unroll
      for (int n = 0; n < 4; n++) {
        bf16x4 pk;
#pragma unroll
        for (int r = 0; r < 4; r++) {
          float v = pv[n][r];
          if (mode == 1 && (t0 + n * 16 + lg4 + r) <= srow) v = 0.0f;
          pk[r] = (bf16_t)v;
        }
        *(bf16x4*)&pl[lr * 72 + n * 16 + lg4] = pk;
      }
      const char* vtb = (const char*)&vt_lds[cur][0];
      __builtin_amdgcn_s_setprio(1);
#pragma unroll
      for (int kk = 0; kk < 2; kk++) {
        bf16x8 pb = *(bf16x8*)&pl[lr * 72 + kk * 32 + lg * 8];
        const int fkk = lr * 128 + ((kk * 64 + 16 * lg) ^ swz);
#pragma unroll
        for (int np = 0; np < 4; np++) {
          bf16x8 vtf = *(const bf16x8*)(vtb + np * 2048 + fkk);
          oat[np] = mfma16(vtf, pb, oat[np]);
        }
      }
      __builtin_amdgcn_s_setprio(0);
    }
    __syncthreads();
    cur ^= 1;
  }
  float lsum = lpart;
  lsum += __shfl_xor(lsum, 16);
  lsum += __shfl_xor(lsum, 32);
  const float inv = 1.0f / lsum;
#pragma unroll
  for (int np = 0; np < 4; np++) {
    bf16x4 o4;
#pragma unroll
    for (int r = 0; r < 4; r++) o4[r] = (bf16_t)(oat[np][r] * inv);
    *(bf16x4*)&pl[lr * 72 + np * 16 + lg4] = o4;
  }
  const int es = l >> 2, ec = (l & 3) * 16;
  bf16x8 o0 = *(bf16x8*)&pl[es * 72 + ec];
  bf16x8 o1 = *(bf16x8*)&pl[es * 72 + ec + 8];
  bf16_t* orow = og + (long)(b * 2048 + q0 + w * 16 + es) * HP + h * 64 + ec;
  *(bf16x8*)&orow[0] = o0;
  *(bf16x8*)&orow[8] = o1;
}

extern "C" void kernel_launch(void* const* d_in, const int* in_sizes, int n_in,
                              void* d_out, int out_size, void* d_ws, size_t ws_size,
                              hipStream_t stream) {
  const float* x = (const float*)d_in[0];
  const float* y = (const float*)d_in[1];
  const float* gxg = (const float*)d_in[2];
  const float* gxb = (const float*)d_in[3];
  const float* gyg = (const float*)d_in[4];
  const float* gyb = (const float*)d_in[5];
  const float* Wq = (const float*)d_in[6];
  const float* bq = (const float*)d_in[7];
  const float* Wk = (const float*)d_in[8];
  const float* bk = (const float*)d_in[9];
  const float* Wv = (const float*)d_in[10];
  const float* bv = (const float*)d_in[11];
  const float* Wo = (const float*)d_in[12];
  const float* bo = (const float*)d_in[13];
  const float* gdg = (const float*)d_in[14];
  const float* gdb = (const float*)d_in[15];
  const float* W1 = (const float*)d_in[16];
  const float* b1 = (const float*)d_in[17];
  const float* W2 = (const float*)d_in[18];
  const float* b2 = (const float*)d_in[19];
  const int* maskp = (const int*)d_in[20];
  float* out = (float*)d_out;

  char* ws = (char*)d_ws;
  const long MB = 1024 * 1024;
  bf16_t* xn = (bf16_t*)(ws + 0);
  bf16_t* yn = (bf16_t*)(ws + 8 * MB);
  bf16_t* WqkvT = (bf16_t*)(ws + 16 * MB);
  bf16_t* WoT = (bf16_t*)(ws + 22 * MB);
  bf16_t* W1T = (bf16_t*)(ws + 24 * MB);
  bf16_t* W2T = (bf16_t*)(ws + 32 * MB);
  bf16_t* qhm = (bf16_t*)(ws + 40 * MB);
  bf16_t* vTb = (bf16_t*)(ws + 64 * MB);
  bf16_t* ob = (bf16_t*)(ws + 0);
  bf16_t* xd = (bf16_t*)(ws + 8 * MB);
  bf16_t* hb = (bf16_t*)(ws + 40 * MB);
  bf16_t* w2part = (bf16_t*)(ws + 0);  // [4][4096][1024] bf16 = 32MB; xn/ob/xd dead by W2
  bf16_t* khm = qhm + 4194304;

  prep_all<<<11264, 256, 0, stream>>>(Wq, Wk, Wv, Wo, W1, W2, WqkvT, WoT, W1T, W2T, x, y, gxg,
                                      gxb, gyg, gyb, xn, yn);
  gemm32<5, 128, 12><<<dim3(24, 32), 256, 0, stream>>>(xn, yn, WqkvT, bq, bk, bv, vTb, qhm,
                                                       4096, 3072, 1024);
  attn_kernel<<<dim3(32, 16), 512, 0, stream>>>(qhm, khm, vTb, ob, maskp);
  gemm64<1, 64><<<dim3(16, 32), 256, 0, stream>>>(ob, WoT, bo, x, out, 4096, 1024, 1024);
  ln_kernel<<<4096, 256, 0, stream>>>(out, gdg, gdb, xd);
  gemm256<2, 4><<<dim3(16, 16), 512, 0, stream>>>(xd, W1T, b1, hb, 4096, 4096, 1024);
  gemm256<7, 4><<<dim3(4, 16, 4), 512, 0, stream>>>(hb, W2T, nullptr, w2part, 4096, 1024, 4096);
  reduce_w2<<<4096, 256, 0, stream>>>(w2part, b2, out);
}

// Round 20
// 220.381 us; speedup vs baseline: 1.0593x; 1.0013x over previous
//
#include <hip/hip_runtime.h>
#include <hip/hip_bf16.h>
#include <math.h>

// B=2, SX=SY=2048, XD=YD=1024, P=64, H=16, MULT=4
typedef __bf16 bf16_t;
typedef __bf16 bf16x8 __attribute__((ext_vector_type(8)));
typedef __bf16 bf16x4 __attribute__((ext_vector_type(4)));
typedef float f32x4 __attribute__((ext_vector_type(4)));

#define QSCALE 0.18033688011112042f /* 0.125 * log2(e): scores in log2 units */

static __device__ __forceinline__ f32x4 mfma16(bf16x8 a, bf16x8 b, f32x4 c) {
  return __builtin_amdgcn_mfma_f32_16x16x32_bf16(a, b, c, 0, 0, 0);
}

static __device__ __forceinline__ float exp2_fast(float x) {
  float r;
  asm("v_exp_f32 %0, %1" : "=v"(r) : "v"(x));
  return r;
}

// tanh-form GELU: 0.5x(1+tanh(u)) = x*e/(e+1), e = exp(2u), u = c1*x + c2*x^3.
static __device__ __forceinline__ float gelu_f(float x) {
  const float u = x * (0.7978845608028654f + 0.03567740813636141f * x * x);
  const float a = fminf(u * 2.885390081777927f, 126.0f);
  const float e = exp2_fast(a);
  float r;
  asm("v_rcp_f32 %0, %1" : "=v"(r) : "v"(e + 1.0f));
  return x * e * r;
}

typedef __attribute__((address_space(1))) const void as1_void;
typedef __attribute__((address_space(3))) void as3_void;
static __device__ __forceinline__ void gload16(const void* g, void* s) {
  __builtin_amdgcn_global_load_lds((as1_void*)g, (as3_void*)s, 16, 0, 0);
}

// head-major index: [b][h][s][p] from (row = b*2048+s, col = h*64+p)
static __device__ __forceinline__ long hmi(int row, int col) {
  return ((((long)(row >> 11) * 16 + (col >> 6)) * 2048) + (row & 2047)) * 64 + (col & 63);
}

// -------- merged prep: 6 weight transposes + both input LayerNorms, one launch --------
__global__ __launch_bounds__(256) void prep_all(
    const float* __restrict__ Wq, const float* __restrict__ Wk, const float* __restrict__ Wv,
    const float* __restrict__ Wo, const float* __restrict__ W1, const float* __restrict__ W2,
    bf16_t* __restrict__ WqkvT, bf16_t* __restrict__ WoT, bf16_t* __restrict__ W1T,
    bf16_t* __restrict__ W2T, const float* __restrict__ x, const float* __restrict__ y,
    const float* __restrict__ gx, const float* __restrict__ bex, const float* __restrict__ gy,
    const float* __restrict__ bey, bf16_t* __restrict__ xn, bf16_t* __restrict__ yn) {
  const int bid = blockIdx.x;
  if (bid >= 3072) {
    const int lrow = bid - 3072;
    const float* in = lrow < 4096 ? x : y;
    const float* g = lrow < 4096 ? gx : gy;
    const float* be = lrow < 4096 ? bex : bey;
    bf16_t* out = lrow < 4096 ? xn : yn;
    const int row = lrow & 4095;
    const int t = threadIdx.x;
    const float4 xv = ((const float4*)(in + (long)row * 1024))[t];
    float s1 = xv.x + xv.y + xv.z + xv.w;
    float s2 = xv.x * xv.x + xv.y * xv.y + xv.z * xv.z + xv.w * xv.w;
#pragma unroll
    for (int m = 1; m < 64; m <<= 1) {
      s1 += __shfl_xor(s1, m);
      s2 += __shfl_xor(s2, m);
    }
    __shared__ float r1[4], r2[4];
    if ((t & 63) == 0) { r1[t >> 6] = s1; r2[t >> 6] = s2; }
    __syncthreads();
    s1 = r1[0] + r1[1] + r1[2] + r1[3];
    s2 = r2[0] + r2[1] + r2[2] + r2[3];
    const float mean = s1 * (1.0f / 1024.0f);
    float var = s2 * (1.0f / 1024.0f) - mean * mean;
    const float rstd = rsqrtf(fmaxf(var, 0.0f) + 1e-5f);
    const float4 gv = ((const float4*)g)[t];
    const float4 bv = ((const float4*)be)[t];
    bf16x4 o;
    o[0] = (bf16_t)((xv.x - mean) * rstd * gv.x + bv.x);
    o[1] = (bf16_t)((xv.y - mean) * rstd * gv.y + bv.y);
    o[2] = (bf16_t)((xv.z - mean) * rstd * gv.z + bv.z);
    o[3] = (bf16_t)((xv.w - mean) * rstd * gv.w + bv.w);
    *(bf16x4*)(out + (long)row * 1024 + t * 4) = o;
    return;
  }
  const float* inp;
  bf16_t* outp;
  int istride, ostride, i0, j0;
  if (bid < 768) {
    const int wsel = bid >> 8, rem = bid & 255;
    const int h = rem >> 4, xt = rem & 15;
    const float* W = wsel == 0 ? Wq : (wsel == 1 ? Wk : Wv);
    inp = W + h * 65536;
    outp = WqkvT + (long)wsel * 1048576 + h * 65536;
    istride = 64; ostride = 1024; i0 = xt * 64; j0 = 0;
  } else if (bid < 1024) {
    const int rem = bid - 768;
    inp = Wo; outp = WoT; istride = 1024; ostride = 1024;
    i0 = (rem & 15) * 64; j0 = (rem >> 4) * 64;
  } else if (bid < 2048) {
    const int rem = bid - 1024;
    inp = W1; outp = W1T; istride = 4096; ostride = 1024;
    i0 = (rem & 15) * 64; j0 = (rem >> 4) * 64;
  } else {
    const int rem = bid - 2048;
    inp = W2; outp = W2T; istride = 1024; ostride = 4096;
    i0 = (rem >> 4) * 64; j0 = (rem & 15) * 64;
  }
  __shared__ bf16_t tile[64][65];
  const int r = threadIdx.x >> 2, cs = (threadIdx.x & 3) * 16;
#pragma unroll
  for (int jj = 0; jj < 16; jj++)
    tile[cs + jj][r] = (bf16_t)inp[(long)(i0 + r) * istride + j0 + cs + jj];
  __syncthreads();
#pragma unroll
  for (int jj = 0; jj < 16; jj++)
    outp[(long)(j0 + r) * ostride + i0 + cs + jj] = tile[r][cs + jj];
}

// ---------------- LayerNorm (standalone, for post-Wo LN) ----------------
__global__ __launch_bounds__(256) void ln_kernel(const float* __restrict__ in,
                                                 const float* __restrict__ g,
                                                 const float* __restrict__ be,
                                                 bf16_t* __restrict__ out) {
  const int row = blockIdx.x, t = threadIdx.x;
  const float4 xv = ((const float4*)(in + (long)row * 1024))[t];
  float s1 = xv.x + xv.y + xv.z + xv.w;
  float s2 = xv.x * xv.x + xv.y * xv.y + xv.z * xv.z + xv.w * xv.w;
#pragma unroll
  for (int m = 1; m < 64; m <<= 1) {
    s1 += __shfl_xor(s1, m);
    s2 += __shfl_xor(s2, m);
  }
  __shared__ float r1[4], r2[4];
  if ((t & 63) == 0) { r1[t >> 6] = s1; r2[t >> 6] = s2; }
  __syncthreads();
  s1 = r1[0] + r1[1] + r1[2] + r1[3];
  s2 = r2[0] + r2[1] + r2[2] + r2[3];
  const float mean = s1 * (1.0f / 1024.0f);
  float var = s2 * (1.0f / 1024.0f) - mean * mean;
  const float rstd = rsqrtf(fmaxf(var, 0.0f) + 1e-5f);
  const float4 gv = ((const float4*)g)[t];
  const float4 bv = ((const float4*)be)[t];
  bf16x4 o;
  o[0] = (bf16_t)((xv.x - mean) * rstd * gv.x + bv.x);
  o[1] = (bf16_t)((xv.y - mean) * rstd * gv.y + bv.y);
  o[2] = (bf16_t)((xv.z - mean) * rstd * gv.z + bv.z);
  o[3] = (bf16_t)((xv.w - mean) * rstd * gv.w + bv.w);
  *(bf16x4*)(out + (long)row * 1024 + t * 4) = o;
}

// ---------------- W2 split-K reduce: out += sum(partials) + b2 ----------------
__global__ __launch_bounds__(256) void reduce_w2(const bf16_t* __restrict__ part,
                                                 const float* __restrict__ b2,
                                                 float* __restrict__ out) {
  const long base = (long)blockIdx.x * 1024 + threadIdx.x * 4;
  float4 o = *(float4*)(out + base);
  const float4 bb = ((const float4*)b2)[threadIdx.x];
  float s0 = 0.0f, s1 = 0.0f, s2 = 0.0f, s3 = 0.0f;
#pragma unroll
  for (int s = 0; s < 4; s++) {
    bf16x4 p = *(const bf16x4*)(part + ((long)s << 22) + base);
    s0 += (float)p[0];
    s1 += (float)p[1];
    s2 += (float)p[2];
    s3 += (float)p[3];
  }
  o.x += s0 + bb.x;
  o.y += s1 + bb.y;
  o.z += s2 + bb.z;
  o.w += s3 + bb.w;
  *(float4*)(out + base) = o;
}

// ====== gemm256: 256x256 tile, 8 waves, BK=64 as 2 kk-halves, 4 phases/K-tile ======
// EPI 2: gelu(bias)->bf16 (W1) ; EPI 7: split-K bf16 partials (W2)
template <int EPI, int RW>
__global__ __launch_bounds__(512, 2) void gemm256(const bf16_t* __restrict__ A,
                                                  const bf16_t* __restrict__ Bt,
                                                  const float* __restrict__ bias,
                                                  void* __restrict__ Cout,
                                                  int M, int N, int K) {
  __shared__ bf16_t a_l[2][2][256 * 32];
  __shared__ bf16_t b_l[2][2][256 * 32];
  const int tid = threadIdx.x, l = tid & 63, wid = tid >> 6;
  const int wr = wid >> 2, wc = wid & 3;
  const int lr = l & 15, lg = l >> 4;
  const int nwg = gridDim.x * gridDim.y * gridDim.z;
  const int orig = (blockIdx.z * gridDim.y + blockIdx.y) * gridDim.x + blockIdx.x;
  int bx, by, ks = 0;
  if (EPI == 7) {
    const int lid = (orig & 7) * (nwg >> 3) + (orig >> 3);
    bx = lid % gridDim.x;
    by = (lid / gridDim.x) % gridDim.y;
    ks = lid / (gridDim.x * gridDim.y);
  } else {
    const int cpx = nwg >> 3;
    const int xcd = orig & 7, ii = orig >> 3;
    const int rpr = gridDim.x / RW;
    bx = (xcd % rpr) * RW + (ii % RW);
    by = (xcd / rpr) * (cpx / RW) + (ii / RW);
  }
  const int m0 = by * 256, n0 = bx * 256;
  const long kbase = (EPI == 7) ? (long)ks << 10 : 0;
  const int nt = (EPI == 7) ? 16 : (K >> 6);
  const int sr0 = tid >> 2, sr1 = 128 + (tid >> 2);
  const int sch2 = ((tid & 3) ^ ((tid >> 3) & 3)) * 8;
  const int sl0 = sr0 * 32 + (tid & 3) * 8;
  const int sl1 = sr1 * 32 + (tid & 3) * 8;
#define STG_A(bufi, kki, kcol)                                                  \
  do {                                                                          \
    gload16(A + (long)(m0 + sr0) * K + (kcol) + sch2, &a_l[bufi][kki][sl0]);    \
    gload16(A + (long)(m0 + sr1) * K + (kcol) + sch2, &a_l[bufi][kki][sl1]);    \
  } while (0)
#define STG_B(bufi, kki, kcol)                                                  \
  do {                                                                          \
    gload16(Bt + (long)(n0 + sr0) * K + (kcol) + sch2, &b_l[bufi][kki][sl0]);   \
    gload16(Bt + (long)(n0 + sr1) * K + (kcol) + sch2, &b_l[bufi][kki][sl1]);   \
  } while (0)
  const int ch = (lg ^ ((lr >> 1) & 3)) * 8;
  f32x4 acc[8][4] = {};
  bf16x8 af[8], bf2[2];
  STG_A(0, 0, kbase + 0); STG_B(0, 0, kbase + 0);
  STG_A(0, 1, kbase + 32); STG_B(0, 1, kbase + 32);
  STG_A(1, 0, kbase + 64); STG_B(1, 0, kbase + 64);
  asm volatile("s_waitcnt vmcnt(8)" ::: "memory");
  __builtin_amdgcn_s_barrier();
  for (int t = 0; t < nt; t++) {
    const int buf = t & 1, nbuf = buf ^ 1;
    const long kc = kbase + (long)t * 64;
#define RD_A(kki)                                                      \
  _Pragma("unroll") for (int m = 0; m < 8; m++) af[m] =                \
      *(const bf16x8*)&a_l[buf][kki][(wr * 128 + m * 16 + lr) * 32 + ch];
#define RD_B(kki, nh)                                                  \
  _Pragma("unroll") for (int j = 0; j < 2; j++) bf2[j] =               \
      *(const bf16x8*)&b_l[buf][kki][(wc * 64 + ((nh)*2 + j) * 16 + lr) * 32 + ch];
#define MM(nh)                                                         \
  __builtin_amdgcn_s_setprio(1);                                       \
  _Pragma("unroll") for (int m = 0; m < 8; m++) {                      \
    acc[m][(nh)*2 + 0] = mfma16(af[m], bf2[0], acc[m][(nh)*2 + 0]);    \
    acc[m][(nh)*2 + 1] = mfma16(af[m], bf2[1], acc[m][(nh)*2 + 1]);    \
  }                                                                    \
  __builtin_amdgcn_s_setprio(0);
    RD_A(0); RD_B(0, 0);
    if (t + 1 < nt) { STG_A(nbuf, 1, kc + 96); }
    __builtin_amdgcn_s_barrier();
    asm volatile("s_waitcnt lgkmcnt(0)" ::: "memory");
    __builtin_amdgcn_sched_barrier(0);
    MM(0);
    __builtin_amdgcn_s_barrier();
    RD_B(0, 1);
    if (t + 1 < nt) { STG_B(nbuf, 1, kc + 96); }
    if (t + 1 < nt) asm volatile("s_waitcnt vmcnt(8)" ::: "memory");
    else            asm volatile("s_waitcnt vmcnt(0)" ::: "memory");
    __builtin_amdgcn_s_barrier();
    asm volatile("s_waitcnt lgkmcnt(0)" ::: "memory");
    __builtin_amdgcn_sched_barrier(0);
    MM(1);
    __builtin_amdgcn_s_barrier();
    RD_A(1); RD_B(1, 0);
    if (t + 2 < nt) { STG_A(buf, 0, kc + 128); }
    __builtin_amdgcn_s_barrier();
    asm volatile("s_waitcnt lgkmcnt(0)" ::: "memory");
    __builtin_amdgcn_sched_barrier(0);
    MM(0);
    __builtin_amdgcn_s_barrier();
    RD_B(1, 1);
    if (t + 2 < nt) { STG_B(buf, 0, kc + 128); }
    if (t + 2 < nt)      asm volatile("s_waitcnt vmcnt(8)" ::: "memory");
    else if (t + 1 < nt) asm volatile("s_waitcnt vmcnt(4)" ::: "memory");
    __builtin_amdgcn_s_barrier();
    asm volatile("s_waitcnt lgkmcnt(0)" ::: "memory");
    __builtin_amdgcn_sched_barrier(0);
    MM(1);
    __builtin_amdgcn_s_barrier();
  }
#undef RD_A
#undef RD_B
#undef MM
#undef STG_A
#undef STG_B
#pragma unroll
  for (int m = 0; m < 8; m++)
#pragma unroll
    for (int n = 0; n < 4; n++) {
      const int row_b = m0 + wr * 128 + m * 16 + lg * 4;
      const int col = n0 + wc * 64 + n * 16 + lr;
      if (EPI == 2) {
        const float bia = bias[col];
#pragma unroll
        for (int r = 0; r < 4; r++) {
          const long idx = (long)(row_b + r) * N + col;
          ((bf16_t*)Cout)[idx] = (bf16_t)gelu_f(acc[m][n][r] + bia);
        }
      } else if (EPI == 7) {
        bf16_t* part = (bf16_t*)Cout + ((long)ks << 22);
#pragma unroll
        for (int r = 0; r < 4; r++)
          part[(long)(row_b + r) * N + col] = (bf16_t)acc[m][n][r];
      }
    }
}

// ---------------- GEMM BK=32 (QKV): 3-buffer, counted vmcnt, 2D XCD regions ----------------
template <int EPI, int BN, int RW>
__global__ __launch_bounds__(256) void gemm32(const bf16_t* __restrict__ A,
                                              const bf16_t* __restrict__ A2,
                                              const bf16_t* __restrict__ Bt,
                                              const float* __restrict__ bias,
                                              const float* __restrict__ biasB,
                                              const float* __restrict__ biasC,
                                              bf16_t* __restrict__ aux,
                                              void* __restrict__ Cout,
                                              int M, int N, int K) {
  constexpr int NF = BN / 32;
  constexpr int NBI = BN / 64;
  __shared__ bf16_t a_lds[3][128 * 32];
  __shared__ bf16_t b_lds[3][BN * 32];
  const int tid = threadIdx.x, l = tid & 63, w = tid >> 6;
  const int wr = w >> 1, wc = w & 1;
  const int nwg = gridDim.x * gridDim.y;
  const int orig = blockIdx.y * gridDim.x + blockIdx.x;
  const int cpx = nwg >> 3;
  const int xcd = orig & 7, ii = orig >> 3;
  const int rpr = gridDim.x / RW;
  const int bx = (xcd % rpr) * RW + (ii % RW);
  const int by = (xcd / rpr) * (cpx / RW) + (ii / RW);
  const int m0 = by * 128, n0 = bx * BN;
  const bf16_t* Ause = (EPI == 5 && n0 >= 1024) ? A2 : A;
  const int lr = l & 15, lg = l >> 4;
  long a_src[2];
  int a_dst[2];
#pragma unroll
  for (int i = 0; i < 2; i++) {
    const int row = i * 64 + (tid >> 2);
    const int sc = ((tid & 3) ^ ((row >> 1) & 3)) * 8;
    a_src[i] = (long)(m0 + row) * K + sc;
    a_dst[i] = (i * 64 + w * 16) * 32;
  }
  long b_src[NBI];
#pragma unroll
  for (int i = 0; i < NBI; i++) {
    const int row = i * 64 + (tid >> 2);
    const int sc = ((tid & 3) ^ ((row >> 1) & 3)) * 8;
    b_src[i] = (long)(n0 + row) * K + sc;
  }
  const int nk = K >> 5;
  f32x4 acc[4][NF] = {};
#pragma unroll
  for (int tt = 0; tt < 2; tt++) {
#pragma unroll
    for (int i = 0; i < 2; i++) gload16(Ause + a_src[i] + tt * 32, &a_lds[tt][a_dst[i]]);
#pragma unroll
    for (int i = 0; i < NBI; i++) gload16(Bt + b_src[i] + tt * 32, &b_lds[tt][a_dst[i]]);
  }
  int cu = 0;
  for (int t = 0; t < nk; t++) {
    if (t + 1 < nk) asm volatile("s_waitcnt vmcnt(4)" ::: "memory");
    else            asm volatile("s_waitcnt vmcnt(0)" ::: "memory");
    __builtin_amdgcn_s_barrier();
    __builtin_amdgcn_sched_barrier(0);
    if (t + 2 < nk) {
      const long k0 = (long)(t + 2) * 32;
      const int nb = cu >= 1 ? cu - 1 : 2;
#pragma unroll
      for (int i = 0; i < 2; i++) gload16(Ause + a_src[i] + k0, &a_lds[nb][a_dst[i]]);
#pragma unroll
      for (int i = 0; i < NBI; i++) gload16(Bt + b_src[i] + k0, &b_lds[nb][a_dst[i]]);
    }
    const char* ab = (const char*)&a_lds[cu][0];
    const char* bb = (const char*)&b_lds[cu][0];
    bf16x8 af[4], bfr[NF];
#pragma unroll
    for (int m = 0; m < 4; m++) {
      const int row = wr * 64 + m * 16 + lr;
      af[m] = *(const bf16x8*)(ab + row * 64 + 16 * (lg ^ ((row >> 1) & 3)));
    }
#pragma unroll
    for (int n = 0; n < NF; n++) {
      const int row = wc * (BN / 2) + n * 16 + lr;
      bfr[n] = *(const bf16x8*)(bb + row * 64 + 16 * (lg ^ ((row >> 1) & 3)));
    }
    __builtin_amdgcn_s_setprio(1);
#pragma unroll
    for (int m = 0; m < 4; m++)
#pragma unroll
      for (int n = 0; n < NF; n++) acc[m][n] = mfma16(af[m], bfr[n], acc[m][n]);
    __builtin_amdgcn_s_setprio(0);
    cu = cu < 2 ? cu + 1 : 0;
  }
#pragma unroll
  for (int m = 0; m < 4; m++)
#pragma unroll
    for (int n = 0; n < NF; n++) {
      const int row_b = m0 + wr * 64 + m * 16 + (l >> 4) * 4;
      const int col = n0 + wc * (BN / 2) + n * 16 + lr;
      if (EPI == 5) {
        if (col < 1024) {
          const float bia = bias[col];
#pragma unroll
          for (int r = 0; r < 4; r++)
            ((bf16_t*)Cout)[hmi(row_b + r, col)] = (bf16_t)((acc[m][n][r] + bia) * QSCALE);
        } else if (col < 2048) {
          const float bia = biasB[col - 1024];
#pragma unroll
          for (int r = 0; r < 4; r++)
            ((bf16_t*)Cout + 4194304)[hmi(row_b + r, col - 1024)] =
                (bf16_t)(acc[m][n][r] + bia);
        } else {
          const int vcol = col - 2048;
          const float bia = biasC[vcol];
          bf16x4 vv;
#pragma unroll
          for (int r = 0; r < 4; r++) vv[r] = (bf16_t)(acc[m][n][r] + bia);
          const int bb2 = row_b >> 11, tt = row_b & 2047;
          *(bf16x4*)&aux[(((long)(bb2 << 4) + (vcol >> 6)) * 64 + (vcol & 63)) * 2048 + tt] = vv;
        }
      }
    }
}

// ---------------- GEMM BK=64 (Wo: BN=64, 48KB LDS): EPI 1 = bias+res -> fp32 ----------------
template <int EPI, int BN>
__global__ __launch_bounds__(256) void gemm64(const bf16_t* __restrict__ A,
                                              const bf16_t* __restrict__ Bt,
                                              const float* __restrict__ bias,
                                              const float* __restrict__ res,
                                              void* __restrict__ Cout,
                                              int M, int N, int K) {
  constexpr int NF = BN / 32;
  constexpr int NBI = BN / 32;
  __shared__ bf16_t a_lds[2][128 * 64];
  __shared__ bf16_t b_lds[2][BN * 64];
  const int tid = threadIdx.x, l = tid & 63, w = tid >> 6;
  const int wr = w >> 1, wc = w & 1;
  const int nwg = gridDim.x * gridDim.y;
  const int orig = blockIdx.y * gridDim.x + blockIdx.x;
  const int lid = (orig & 7) * (nwg >> 3) + (orig >> 3);
  const int bx = lid % gridDim.x, by = lid / gridDim.x;
  const int m0 = by * 128, n0 = bx * BN;
  const int lr = l & 15, lg = l >> 4;
  long a_src[4];
  int ldst[4];
#pragma unroll
  for (int i = 0; i < 4; i++) {
    const int row = i * 32 + w * 8 + (l >> 3);
    const int sc = ((l & 7) ^ (row & 7)) * 8;
    a_src[i] = (long)(m0 + row) * K + sc;
    ldst[i] = (i * 32 + w * 8) * 64;
  }
  long b_src[NBI];
#pragma unroll
  for (int i = 0; i < NBI; i++) {
    const int row = i * 32 + w * 8 + (l >> 3);
    const int sc = ((l & 7) ^ (row & 7)) * 8;
    b_src[i] = (long)(n0 + row) * K + sc;
  }
  const int nk = K >> 6;
  f32x4 acc[4][NF] = {};
#pragma unroll
  for (int i = 0; i < 4; i++) gload16(A + a_src[i], &a_lds[0][ldst[i]]);
#pragma unroll
  for (int i = 0; i < NBI; i++) gload16(Bt + b_src[i], &b_lds[0][ldst[i]]);
  __syncthreads();
  const int sw = (lr & 7) << 4;
  int cur = 0;
  for (int t = 0; t < nk; t++) {
    if (t + 1 < nk) {
      const long k0 = (long)(t + 1) * 64;
#pragma unroll
      for (int i = 0; i < 4; i++) gload16(A + a_src[i] + k0, &a_lds[cur ^ 1][ldst[i]]);
#pragma unroll
      for (int i = 0; i < NBI; i++) gload16(Bt + b_src[i] + k0, &b_lds[cur ^ 1][ldst[i]]);
    }
    const char* ab = (const char*)&a_lds[cur][0];
    const char* bb = (const char*)&b_lds[cur][0];
    bf16x8 af[4][2], bfr[NF][2];
#pragma unroll
    for (int m = 0; m < 4; m++) {
      const int rb = (wr * 64 + m * 16 + lr) * 128;
      af[m][0] = *(const bf16x8*)(ab + rb + ((16 * lg) ^ sw));
      af[m][1] = *(const bf16x8*)(ab + rb + ((16 * lg + 64) ^ sw));
    }
#pragma unroll
    for (int n = 0; n < NF; n++) {
      const int rb = (wc * (BN / 2) + n * 16 + lr) * 128;
      bfr[n][0] = *(const bf16x8*)(bb + rb + ((16 * lg) ^ sw));
      bfr[n][1] = *(const bf16x8*)(bb + rb + ((16 * lg + 64) ^ sw));
    }
    __builtin_amdgcn_s_setprio(1);
#pragma unroll
    for (int kk = 0; kk < 2; kk++)
#pragma unroll
      for (int m = 0; m < 4; m++)
#pragma unroll
        for (int n = 0; n < NF; n++)
          acc[m][n] = mfma16(af[m][kk], bfr[n][kk], acc[m][n]);
    __builtin_amdgcn_s_setprio(0);
    __syncthreads();
    cur ^= 1;
  }
#pragma unroll
  for (int m = 0; m < 4; m++)
#pragma unroll
    for (int n = 0; n < NF; n++) {
      const int row_b = m0 + wr * 64 + m * 16 + (l >> 4) * 4;
      const int col = n0 + wc * (BN / 2) + n * 16 + lr;
      const float bia = bias[col];
#pragma unroll
      for (int r = 0; r < 4; r++) {
        const long idx = (long)(row_b + r) * N + col;
        ((float*)Cout)[idx] = acc[m][n][r] + bia + res[idx];
      }
    }
}

// ---------------- fused attention v9: QBLK=128, 8 waves (512 thr), 16 rows/wave --------
__global__ __launch_bounds__(512) void attn_kernel(const bf16_t* __restrict__ qhm,
                                                   const bf16_t* __restrict__ khm,
                                                   const bf16_t* __restrict__ vtg,
                                                   bf16_t* __restrict__ og,
                                                   const int* __restrict__ maskp) {
  const int T = 2048, HP = 1024;
  __shared__ bf16_t k_lds[2][64 * 64];
  __shared__ bf16_t vt_lds[2][64 * 64];
  __shared__ bf16_t p_lds[8 * 16 * 72];
  const int bh = blockIdx.x, b = bh >> 4, h = bh & 15;
  const int q0 = blockIdx.y * 128;
  const int tid = threadIdx.x, l = tid & 63, w = tid >> 6;  // w in [0,8)
  const int lr = l & 15, lg = l >> 4, lg4 = lg * 4;
  const int srow = q0 + w * 16 + lr;
  const bf16_t* kbase = khm + (long)bh * T * 64;
  const bf16_t* vbase = vtg + (long)bh * 64 * T;
  const bf16_t* qr = qhm + ((long)bh * 2048 + srow) * 64 + lg * 8;
  bf16x8 qf0 = *(const bf16x8*)qr;
  bf16x8 qf1 = *(const bf16x8*)(qr + 32);
  bf16_t* pl = &p_lds[w * 16 * 72];
  float lpart = 0.0f;
  f32x4 oat[4] = {};

  const int swz = (lr & 7) << 4;
  const int fo0 = lr * 128 + ((16 * lg) ^ swz);
  const int fo1 = lr * 128 + ((64 + 16 * lg) ^ swz);

  const bool do_mask = (maskp[0] != 0);
  const int nM = do_mask ? (q0 >> 6) : 0;
  const int nt = T >> 6;

  const int srow8 = l >> 3, sch = l & 7;
  const int ssc = (sch ^ srow8) * 8;
  const int srw = w * 8 + srow8;
  int cur = 0;
  {
    const bool needV = (nM == 0);
    gload16(kbase + (long)srw * 64 + ssc, &k_lds[0][w * 512]);
    if (needV) gload16(vbase + (long)srw * 2048 + 0 + ssc, &vt_lds[0][w * 512]);
  }
  __syncthreads();

  for (int t = 0; t < nt; t++) {
    const int t0 = t << 6;
    const int mode = (t < nM) ? 0 : ((do_mask && t < nM + 2) ? 1 : 2);
    if (t + 1 < nt) {
      const int t1 = (t + 1) << 6;
      const bool needV = (t + 1) >= nM;
      gload16(kbase + (long)(t1 + srw) * 64 + ssc, &k_lds[cur ^ 1][w * 512]);
      if (needV) gload16(vbase + (long)srw * 2048 + t1 + ssc, &vt_lds[cur ^ 1][w * 512]);
    }
    const char* kb = (const char*)&k_lds[cur][0];
    f32x4 sacc[4];
    __builtin_amdgcn_s_setprio(1);
#pragma unroll
    for (int n = 0; n < 4; n++) {
      bf16x8 kf0 = *(const bf16x8*)(kb + n * 2048 + fo0);
      bf16x8 kf1 = *(const bf16x8*)(kb + n * 2048 + fo1);
      f32x4 z = {0.0f, 0.0f, 0.0f, 0.0f};
      z = mfma16(kf0, qf0, z);
      sacc[n] = mfma16(kf1, qf1, z);
    }
    __builtin_amdgcn_s_setprio(0);
    float pv[4][4], psn[4];
#pragma unroll
    for (int n = 0; n < 4; n++) {
      pv[n][0] = exp2_fast(sacc[n][0]);
      pv[n][1] = exp2_fast(sacc[n][1]);
      pv[n][2] = exp2_fast(sacc[n][2]);
      pv[n][3] = exp2_fast(sacc[n][3]);
      psn[n] = (pv[n][0] + pv[n][1]) + (pv[n][2] + pv[n][3]);
    }
    lpart += (psn[0] + psn[1]) + (psn[2] + psn[3]);
    if (mode > 0) {
#pragma unroll
      for (int n = 0; n < 4; n++) {
        bf16x4 pk;
#pragma unroll
        for (int r = 0; r < 4; r++) {
          float v = pv[n][r];
          if (mode == 1 && (t0 + n * 16 + lg4 + r) <= srow) v = 0.0f;
          pk[r] = (bf16_t)v;
        }
        *(bf16x4*)&pl[lr * 72 + n * 16 + lg4] = pk;
      }
      const char* vtb = (const char*)&vt_lds[cur][0];
      __builtin_amdgcn_s_setprio(1);
#pragma unroll
      for (int kk = 0; kk < 2; kk++) {
        bf16x8 pb = *(bf16x8*)&pl[lr * 72 + kk * 32 + lg * 8];
        const int fkk = lr * 128 + ((kk * 64 + 16 * lg) ^ swz);
#pragma unroll
        for (int np = 0; np < 4; np++) {
          bf16x8 vtf = *(const bf16x8*)(vtb + np * 2048 + fkk);
          oat[np] = mfma16(vtf, pb, oat[np]);
        }
      }
      __builtin_amdgcn_s_setprio(0);
    }
    __syncthreads();
    cur ^= 1;
  }
  float lsum = lpart;
  lsum += __shfl_xor(lsum, 16);
  lsum += __shfl_xor(lsum, 32);
  const float inv = 1.0f / lsum;
#pragma unroll
  for (int np = 0; np < 4; np++) {
    bf16x4 o4;
#pragma unroll
    for (int r = 0; r < 4; r++) o4[r] = (bf16_t)(oat[np][r] * inv);
    *(bf16x4*)&pl[lr * 72 + np * 16 + lg4] = o4;
  }
  const int es = l >> 2, ec = (l & 3) * 16;
  bf16x8 o0 = *(bf16x8*)&pl[es * 72 + ec];
  bf16x8 o1 = *(bf16x8*)&pl[es * 72 + ec + 8];
  bf16_t* orow = og + (long)(b * 2048 + q0 + w * 16 + es) * HP + h * 64 + ec;
  *(bf16x8*)&orow[0] = o0;
  *(bf16x8*)&orow[8] = o1;
}

extern "C" void kernel_launch(void* const* d_in, const int* in_sizes, int n_in,
                              void* d_out, int out_size, void* d_ws, size_t ws_size,
                              hipStream_t stream) {
  const float* x = (const float*)d_in[0];
  const float* y = (const float*)d_in[1];
  const float* gxg = (const float*)d_in[2];
  const float* gxb = (const float*)d_in[3];
  const float* gyg = (const float*)d_in[4];
  const float* gyb = (const float*)d_in[5];
  const float* Wq = (const float*)d_in[6];
  const float* bq = (const float*)d_in[7];
  const float* Wk = (const float*)d_in[8];
  const float* bk = (const float*)d_in[9];
  const float* Wv = (const float*)d_in[10];
  const float* bv = (const float*)d_in[11];
  const float* Wo = (const float*)d_in[12];
  const float* bo = (const float*)d_in[13];
  const float* gdg = (const float*)d_in[14];
  const float* gdb = (const float*)d_in[15];
  const float* W1 = (const float*)d_in[16];
  const float* b1 = (const float*)d_in[17];
  const float* W2 = (const float*)d_in[18];
  const float* b2 = (const float*)d_in[19];
  const int* maskp = (const int*)d_in[20];
  float* out = (float*)d_out;

  char* ws = (char*)d_ws;
  const long MB = 1024 * 1024;
  bf16_t* xn = (bf16_t*)(ws + 0);
  bf16_t* yn = (bf16_t*)(ws + 8 * MB);
  bf16_t* WqkvT = (bf16_t*)(ws + 16 * MB);
  bf16_t* WoT = (bf16_t*)(ws + 22 * MB);
  bf16_t* W1T = (bf16_t*)(ws + 24 * MB);
  bf16_t* W2T = (bf16_t*)(ws + 32 * MB);
  bf16_t* qhm = (bf16_t*)(ws + 40 * MB);
  bf16_t* vTb = (bf16_t*)(ws + 64 * MB);
  bf16_t* ob = (bf16_t*)(ws + 0);
  bf16_t* xd = (bf16_t*)(ws + 8 * MB);
  bf16_t* hb = (bf16_t*)(ws + 40 * MB);
  bf16_t* w2part = (bf16_t*)(ws + 0);  // [4][4096][1024] bf16 = 32MB; xn/ob/xd dead by W2
  bf16_t* khm = qhm + 4194304;

  prep_all<<<11264, 256, 0, stream>>>(Wq, Wk, Wv, Wo, W1, W2, WqkvT, WoT, W1T, W2T, x, y, gxg,
                                      gxb, gyg, gyb, xn, yn);
  gemm32<5, 128, 12><<<dim3(24, 32), 256, 0, stream>>>(xn, yn, WqkvT, bq, bk, bv, vTb, qhm,
                                                       4096, 3072, 1024);
  attn_kernel<<<dim3(32, 16), 512, 0, stream>>>(qhm, khm, vTb, ob, maskp);
  gemm64<1, 64><<<dim3(16, 32), 256, 0, stream>>>(ob, WoT, bo, x, out, 4096, 1024, 1024);
  ln_kernel<<<4096, 256, 0, stream>>>(out, gdg, gdb, xd);
  gemm256<2, 4><<<dim3(16, 16), 512, 0, stream>>>(xd, W1T, b1, hb, 4096, 4096, 1024);
  gemm256<7, 4><<<dim3(4, 16, 4), 512, 0, stream>>>(hb, W2T, nullptr, w2part, 4096, 1024, 4096);
  reduce_w2<<<4096, 256, 0, stream>>>(w2part, b2, out);
}

// Round 21
// 220.176 us; speedup vs baseline: 1.0603x; 1.0009x over previous
//
#include <hip/hip_runtime.h>
#include <hip/hip_bf16.h>
#include <math.h>

// B=2, SX=SY=2048, XD=YD=1024, P=64, H=16, MULT=4
typedef __bf16 bf16_t;
typedef __bf16 bf16x8 __attribute__((ext_vector_type(8)));
typedef __bf16 bf16x4 __attribute__((ext_vector_type(4)));
typedef float f32x4 __attribute__((ext_vector_type(4)));

#define QSCALE 0.18033688011112042f /* 0.125 * log2(e): scores in log2 units */

static __device__ __forceinline__ f32x4 mfma16(bf16x8 a, bf16x8 b, f32x4 c) {
  return __builtin_amdgcn_mfma_f32_16x16x32_bf16(a, b, c, 0, 0, 0);
}

static __device__ __forceinline__ float exp2_fast(float x) {
  float r;
  asm("v_exp_f32 %0, %1" : "=v"(r) : "v"(x));
  return r;
}

// tanh-form GELU: 0.5x(1+tanh(u)) = x*e/(e+1), e = exp(2u), u = c1*x + c2*x^3.
static __device__ __forceinline__ float gelu_f(float x) {
  const float u = x * (0.7978845608028654f + 0.03567740813636141f * x * x);
  const float a = fminf(u * 2.885390081777927f, 126.0f);
  const float e = exp2_fast(a);
  float r;
  asm("v_rcp_f32 %0, %1" : "=v"(r) : "v"(e + 1.0f));
  return x * e * r;
}

typedef __attribute__((address_space(1))) const void as1_void;
typedef __attribute__((address_space(3))) void as3_void;
static __device__ __forceinline__ void gload16(const void* g, void* s) {
  __builtin_amdgcn_global_load_lds((as1_void*)g, (as3_void*)s, 16, 0, 0);
}

// head-major index: [b][h][s][p] from (row = b*2048+s, col = h*64+p)
static __device__ __forceinline__ long hmi(int row, int col) {
  return ((((long)(row >> 11) * 16 + (col >> 6)) * 2048) + (row & 2047)) * 64 + (col & 63);
}

// -------- merged prep: 6 weight transposes + both input LayerNorms, one launch --------
__global__ __launch_bounds__(256) void prep_all(
    const float* __restrict__ Wq, const float* __restrict__ Wk, const float* __restrict__ Wv,
    const float* __restrict__ Wo, const float* __restrict__ W1, const float* __restrict__ W2,
    bf16_t* __restrict__ WqkvT, bf16_t* __restrict__ WoT, bf16_t* __restrict__ W1T,
    bf16_t* __restrict__ W2T, const float* __restrict__ x, const float* __restrict__ y,
    const float* __restrict__ gx, const float* __restrict__ bex, const float* __restrict__ gy,
    const float* __restrict__ bey, bf16_t* __restrict__ xn, bf16_t* __restrict__ yn) {
  const int bid = blockIdx.x;
  if (bid >= 3072) {
    const int lrow = bid - 3072;
    const float* in = lrow < 4096 ? x : y;
    const float* g = lrow < 4096 ? gx : gy;
    const float* be = lrow < 4096 ? bex : bey;
    bf16_t* out = lrow < 4096 ? xn : yn;
    const int row = lrow & 4095;
    const int t = threadIdx.x;
    const float4 xv = ((const float4*)(in + (long)row * 1024))[t];
    float s1 = xv.x + xv.y + xv.z + xv.w;
    float s2 = xv.x * xv.x + xv.y * xv.y + xv.z * xv.z + xv.w * xv.w;
#pragma unroll
    for (int m = 1; m < 64; m <<= 1) {
      s1 += __shfl_xor(s1, m);
      s2 += __shfl_xor(s2, m);
    }
    __shared__ float r1[4], r2[4];
    if ((t & 63) == 0) { r1[t >> 6] = s1; r2[t >> 6] = s2; }
    __syncthreads();
    s1 = r1[0] + r1[1] + r1[2] + r1[3];
    s2 = r2[0] + r2[1] + r2[2] + r2[3];
    const float mean = s1 * (1.0f / 1024.0f);
    float var = s2 * (1.0f / 1024.0f) - mean * mean;
    const float rstd = rsqrtf(fmaxf(var, 0.0f) + 1e-5f);
    const float4 gv = ((const float4*)g)[t];
    const float4 bv = ((const float4*)be)[t];
    bf16x4 o;
    o[0] = (bf16_t)((xv.x - mean) * rstd * gv.x + bv.x);
    o[1] = (bf16_t)((xv.y - mean) * rstd * gv.y + bv.y);
    o[2] = (bf16_t)((xv.z - mean) * rstd * gv.z + bv.z);
    o[3] = (bf16_t)((xv.w - mean) * rstd * gv.w + bv.w);
    *(bf16x4*)(out + (long)row * 1024 + t * 4) = o;
    return;
  }
  const float* inp;
  bf16_t* outp;
  int istride, ostride, i0, j0;
  if (bid < 768) {
    const int wsel = bid >> 8, rem = bid & 255;
    const int h = rem >> 4, xt = rem & 15;
    const float* W = wsel == 0 ? Wq : (wsel == 1 ? Wk : Wv);
    inp = W + h * 65536;
    outp = WqkvT + (long)wsel * 1048576 + h * 65536;
    istride = 64; ostride = 1024; i0 = xt * 64; j0 = 0;
  } else if (bid < 1024) {
    const int rem = bid - 768;
    inp = Wo; outp = WoT; istride = 1024; ostride = 1024;
    i0 = (rem & 15) * 64; j0 = (rem >> 4) * 64;
  } else if (bid < 2048) {
    const int rem = bid - 1024;
    inp = W1; outp = W1T; istride = 4096; ostride = 1024;
    i0 = (rem & 15) * 64; j0 = (rem >> 4) * 64;
  } else {
    const int rem = bid - 2048;
    inp = W2; outp = W2T; istride = 1024; ostride = 4096;
    i0 = (rem >> 4) * 64; j0 = (rem & 15) * 64;
  }
  __shared__ bf16_t tile[64][65];
  const int r = threadIdx.x >> 2, cs = (threadIdx.x & 3) * 16;
#pragma unroll
  for (int jj = 0; jj < 16; jj++)
    tile[cs + jj][r] = (bf16_t)inp[(long)(i0 + r) * istride + j0 + cs + jj];
  __syncthreads();
#pragma unroll
  for (int jj = 0; jj < 16; jj++)
    outp[(long)(j0 + r) * ostride + i0 + cs + jj] = tile[r][cs + jj];
}

// ---------------- LayerNorm (standalone, for post-Wo LN) ----------------
__global__ __launch_bounds__(256) void ln_kernel(const float* __restrict__ in,
                                                 const float* __restrict__ g,
                                                 const float* __restrict__ be,
                                                 bf16_t* __restrict__ out) {
  const int row = blockIdx.x, t = threadIdx.x;
  const float4 xv = ((const float4*)(in + (long)row * 1024))[t];
  float s1 = xv.x + xv.y + xv.z + xv.w;
  float s2 = xv.x * xv.x + xv.y * xv.y + xv.z * xv.z + xv.w * xv.w;
#pragma unroll
  for (int m = 1; m < 64; m <<= 1) {
    s1 += __shfl_xor(s1, m);
    s2 += __shfl_xor(s2, m);
  }
  __shared__ float r1[4], r2[4];
  if ((t & 63) == 0) { r1[t >> 6] = s1; r2[t >> 6] = s2; }
  __syncthreads();
  s1 = r1[0] + r1[1] + r1[2] + r1[3];
  s2 = r2[0] + r2[1] + r2[2] + r2[3];
  const float mean = s1 * (1.0f / 1024.0f);
  float var = s2 * (1.0f / 1024.0f) - mean * mean;
  const float rstd = rsqrtf(fmaxf(var, 0.0f) + 1e-5f);
  const float4 gv = ((const float4*)g)[t];
  const float4 bv = ((const float4*)be)[t];
  bf16x4 o;
  o[0] = (bf16_t)((xv.x - mean) * rstd * gv.x + bv.x);
  o[1] = (bf16_t)((xv.y - mean) * rstd * gv.y + bv.y);
  o[2] = (bf16_t)((xv.z - mean) * rstd * gv.z + bv.z);
  o[3] = (bf16_t)((xv.w - mean) * rstd * gv.w + bv.w);
  *(bf16x4*)(out + (long)row * 1024 + t * 4) = o;
}

// ---------------- W2 split-K reduce: out += sum(partials) + b2 ----------------
__global__ __launch_bounds__(256) void reduce_w2(const bf16_t* __restrict__ part,
                                                 const float* __restrict__ b2,
                                                 float* __restrict__ out) {
  const long base = (long)blockIdx.x * 1024 + threadIdx.x * 4;
  float4 o = *(float4*)(out + base);
  const float4 bb = ((const float4*)b2)[threadIdx.x];
  float s0 = 0.0f, s1 = 0.0f, s2 = 0.0f, s3 = 0.0f;
#pragma unroll
  for (int s = 0; s < 4; s++) {
    bf16x4 p = *(const bf16x4*)(part + ((long)s << 22) + base);
    s0 += (float)p[0];
    s1 += (float)p[1];
    s2 += (float)p[2];
    s3 += (float)p[3];
  }
  o.x += s0 + bb.x;
  o.y += s1 + bb.y;
  o.z += s2 + bb.z;
  o.w += s3 + bb.w;
  *(float4*)(out + base) = o;
}

// ====== gemm256: 256x256 tile, 8 waves, BK=64 as 2 kk-halves, 4 phases/K-tile ======
// EPI 2: gelu(bias)->bf16 (W1) ; EPI 7: split-K bf16 partials (W2)
template <int EPI, int RW>
__global__ __launch_bounds__(512, 2) void gemm256(const bf16_t* __restrict__ A,
                                                  const bf16_t* __restrict__ Bt,
                                                  const float* __restrict__ bias,
                                                  void* __restrict__ Cout,
                                                  int M, int N, int K) {
  __shared__ bf16_t a_l[2][2][256 * 32];
  __shared__ bf16_t b_l[2][2][256 * 32];
  const int tid = threadIdx.x, l = tid & 63, wid = tid >> 6;
  const int wr = wid >> 2, wc = wid & 3;
  const int lr = l & 15, lg = l >> 4;
  const int nwg = gridDim.x * gridDim.y * gridDim.z;
  const int orig = (blockIdx.z * gridDim.y + blockIdx.y) * gridDim.x + blockIdx.x;
  int bx, by, ks = 0;
  if (EPI == 7) {
    const int lid = (orig & 7) * (nwg >> 3) + (orig >> 3);
    bx = lid % gridDim.x;
    by = (lid / gridDim.x) % gridDim.y;
    ks = lid / (gridDim.x * gridDim.y);
  } else {
    const int cpx = nwg >> 3;
    const int xcd = orig & 7, ii = orig >> 3;
    const int rpr = gridDim.x / RW;
    bx = (xcd % rpr) * RW + (ii % RW);
    by = (xcd / rpr) * (cpx / RW) + (ii / RW);
  }
  const int m0 = by * 256, n0 = bx * 256;
  const long kbase = (EPI == 7) ? (long)ks << 10 : 0;
  const int nt = (EPI == 7) ? 16 : (K >> 6);
  const int sr0 = tid >> 2, sr1 = 128 + (tid >> 2);
  const int sch2 = ((tid & 3) ^ ((tid >> 3) & 3)) * 8;
  const int sl0 = sr0 * 32 + (tid & 3) * 8;
  const int sl1 = sr1 * 32 + (tid & 3) * 8;
#define STG_A(bufi, kki, kcol)                                                  \
  do {                                                                          \
    gload16(A + (long)(m0 + sr0) * K + (kcol) + sch2, &a_l[bufi][kki][sl0]);    \
    gload16(A + (long)(m0 + sr1) * K + (kcol) + sch2, &a_l[bufi][kki][sl1]);    \
  } while (0)
#define STG_B(bufi, kki, kcol)                                                  \
  do {                                                                          \
    gload16(Bt + (long)(n0 + sr0) * K + (kcol) + sch2, &b_l[bufi][kki][sl0]);   \
    gload16(Bt + (long)(n0 + sr1) * K + (kcol) + sch2, &b_l[bufi][kki][sl1]);   \
  } while (0)
  const int ch = (lg ^ ((lr >> 1) & 3)) * 8;
  f32x4 acc[8][4] = {};
  bf16x8 af[8], bf2[2];
  STG_A(0, 0, kbase + 0); STG_B(0, 0, kbase + 0);
  STG_A(0, 1, kbase + 32); STG_B(0, 1, kbase + 32);
  STG_A(1, 0, kbase + 64); STG_B(1, 0, kbase + 64);
  asm volatile("s_waitcnt vmcnt(8)" ::: "memory");
  __builtin_amdgcn_s_barrier();
  for (int t = 0; t < nt; t++) {
    const int buf = t & 1, nbuf = buf ^ 1;
    const long kc = kbase + (long)t * 64;
#define RD_A(kki)                                                      \
  _Pragma("unroll") for (int m = 0; m < 8; m++) af[m] =                \
      *(const bf16x8*)&a_l[buf][kki][(wr * 128 + m * 16 + lr) * 32 + ch];
#define RD_B(kki, nh)                                                  \
  _Pragma("unroll") for (int j = 0; j < 2; j++) bf2[j] =               \
      *(const bf16x8*)&b_l[buf][kki][(wc * 64 + ((nh)*2 + j) * 16 + lr) * 32 + ch];
#define MM(nh)                                                         \
  __builtin_amdgcn_s_setprio(1);                                       \
  _Pragma("unroll") for (int m = 0; m < 8; m++) {                      \
    acc[m][(nh)*2 + 0] = mfma16(af[m], bf2[0], acc[m][(nh)*2 + 0]);    \
    acc[m][(nh)*2 + 1] = mfma16(af[m], bf2[1], acc[m][(nh)*2 + 1]);    \
  }                                                                    \
  __builtin_amdgcn_s_setprio(0);
    RD_A(0); RD_B(0, 0);
    if (t + 1 < nt) { STG_A(nbuf, 1, kc + 96); }
    __builtin_amdgcn_s_barrier();
    asm volatile("s_waitcnt lgkmcnt(0)" ::: "memory");
    __builtin_amdgcn_sched_barrier(0);
    MM(0);
    __builtin_amdgcn_s_barrier();
    RD_B(0, 1);
    if (t + 1 < nt) { STG_B(nbuf, 1, kc + 96); }
    if (t + 1 < nt) asm volatile("s_waitcnt vmcnt(8)" ::: "memory");
    else            asm volatile("s_waitcnt vmcnt(0)" ::: "memory");
    __builtin_amdgcn_s_barrier();
    asm volatile("s_waitcnt lgkmcnt(0)" ::: "memory");
    __builtin_amdgcn_sched_barrier(0);
    MM(1);
    __builtin_amdgcn_s_barrier();
    RD_A(1); RD_B(1, 0);
    if (t + 2 < nt) { STG_A(buf, 0, kc + 128); }
    __builtin_amdgcn_s_barrier();
    asm volatile("s_waitcnt lgkmcnt(0)" ::: "memory");
    __builtin_amdgcn_sched_barrier(0);
    MM(0);
    __builtin_amdgcn_s_barrier();
    RD_B(1, 1);
    if (t + 2 < nt) { STG_B(buf, 0, kc + 128); }
    if (t + 2 < nt)      asm volatile("s_waitcnt vmcnt(8)" ::: "memory");
    else if (t + 1 < nt) asm volatile("s_waitcnt vmcnt(4)" ::: "memory");
    __builtin_amdgcn_s_barrier();
    asm volatile("s_waitcnt lgkmcnt(0)" ::: "memory");
    __builtin_amdgcn_sched_barrier(0);
    MM(1);
    __builtin_amdgcn_s_barrier();
  }
#undef RD_A
#undef RD_B
#undef MM
#undef STG_A
#undef STG_B
#pragma unroll
  for (int m = 0; m < 8; m++)
#pragma unroll
    for (int n = 0; n < 4; n++) {
      const int row_b = m0 + wr * 128 + m * 16 + lg * 4;
      const int col = n0 + wc * 64 + n * 16 + lr;
      if (EPI == 2) {
        const float bia = bias[col];
#pragma unroll
        for (int r = 0; r < 4; r++) {
          const long idx = (long)(row_b + r) * N + col;
          ((bf16_t*)Cout)[idx] = (bf16_t)gelu_f(acc[m][n][r] + bia);
        }
      } else if (EPI == 7) {
        bf16_t* part = (bf16_t*)Cout + ((long)ks << 22);
#pragma unroll
        for (int r = 0; r < 4; r++)
          part[(long)(row_b + r) * N + col] = (bf16_t)acc[m][n][r];
      }
    }
}

// ---------------- GEMM BK=32 (QKV): 3-buffer, counted vmcnt, 2D XCD regions ----------------
template <int EPI, int BN, int RW>
__global__ __launch_bounds__(256) void gemm32(const bf16_t* __restrict__ A,
                                              const bf16_t* __restrict__ A2,
                                              const bf16_t* __restrict__ Bt,
                                              const float* __restrict__ bias,
                                              const float* __restrict__ biasB,
                                              const float* __restrict__ biasC,
                                              bf16_t* __restrict__ aux,
                                              void* __restrict__ Cout,
                                              int M, int N, int K) {
  constexpr int NF = BN / 32;
  constexpr int NBI = BN / 64;
  __shared__ bf16_t a_lds[3][128 * 32];
  __shared__ bf16_t b_lds[3][BN * 32];
  const int tid = threadIdx.x, l = tid & 63, w = tid >> 6;
  const int wr = w >> 1, wc = w & 1;
  const int nwg = gridDim.x * gridDim.y;
  const int orig = blockIdx.y * gridDim.x + blockIdx.x;
  const int cpx = nwg >> 3;
  const int xcd = orig & 7, ii = orig >> 3;
  const int rpr = gridDim.x / RW;
  const int bx = (xcd % rpr) * RW + (ii % RW);
  const int by = (xcd / rpr) * (cpx / RW) + (ii / RW);
  const int m0 = by * 128, n0 = bx * BN;
  const bf16_t* Ause = (EPI == 5 && n0 >= 1024) ? A2 : A;
  const int lr = l & 15, lg = l >> 4;
  long a_src[2];
  int a_dst[2];
#pragma unroll
  for (int i = 0; i < 2; i++) {
    const int row = i * 64 + (tid >> 2);
    const int sc = ((tid & 3) ^ ((row >> 1) & 3)) * 8;
    a_src[i] = (long)(m0 + row) * K + sc;
    a_dst[i] = (i * 64 + w * 16) * 32;
  }
  long b_src[NBI];
#pragma unroll
  for (int i = 0; i < NBI; i++) {
    const int row = i * 64 + (tid >> 2);
    const int sc = ((tid & 3) ^ ((row >> 1) & 3)) * 8;
    b_src[i] = (long)(n0 + row) * K + sc;
  }
  const int nk = K >> 5;
  f32x4 acc[4][NF] = {};
#pragma unroll
  for (int tt = 0; tt < 2; tt++) {
#pragma unroll
    for (int i = 0; i < 2; i++) gload16(Ause + a_src[i] + tt * 32, &a_lds[tt][a_dst[i]]);
#pragma unroll
    for (int i = 0; i < NBI; i++) gload16(Bt + b_src[i] + tt * 32, &b_lds[tt][a_dst[i]]);
  }
  int cu = 0;
  for (int t = 0; t < nk; t++) {
    if (t + 1 < nk) asm volatile("s_waitcnt vmcnt(4)" ::: "memory");
    else            asm volatile("s_waitcnt vmcnt(0)" ::: "memory");
    __builtin_amdgcn_s_barrier();
    __builtin_amdgcn_sched_barrier(0);
    if (t + 2 < nk) {
      const long k0 = (long)(t + 2) * 32;
      const int nb = cu >= 1 ? cu - 1 : 2;
#pragma unroll
      for (int i = 0; i < 2; i++) gload16(Ause + a_src[i] + k0, &a_lds[nb][a_dst[i]]);
#pragma unroll
      for (int i = 0; i < NBI; i++) gload16(Bt + b_src[i] + k0, &b_lds[nb][a_dst[i]]);
    }
    const char* ab = (const char*)&a_lds[cu][0];
    const char* bb = (const char*)&b_lds[cu][0];
    bf16x8 af[4], bfr[NF];
#pragma unroll
    for (int m = 0; m < 4; m++) {
      const int row = wr * 64 + m * 16 + lr;
      af[m] = *(const bf16x8*)(ab + row * 64 + 16 * (lg ^ ((row >> 1) & 3)));
    }
#pragma unroll
    for (int n = 0; n < NF; n++) {
      const int row = wc * (BN / 2) + n * 16 + lr;
      bfr[n] = *(const bf16x8*)(bb + row * 64 + 16 * (lg ^ ((row >> 1) & 3)));
    }
    __builtin_amdgcn_s_setprio(1);
#pragma unroll
    for (int m = 0; m < 4; m++)
#pragma unroll
      for (int n = 0; n < NF; n++) acc[m][n] = mfma16(af[m], bfr[n], acc[m][n]);
    __builtin_amdgcn_s_setprio(0);
    cu = cu < 2 ? cu + 1 : 0;
  }
#pragma unroll
  for (int m = 0; m < 4; m++)
#pragma unroll
    for (int n = 0; n < NF; n++) {
      const int row_b = m0 + wr * 64 + m * 16 + (l >> 4) * 4;
      const int col = n0 + wc * (BN / 2) + n * 16 + lr;
      if (EPI == 5) {
        if (col < 1024) {
          const float bia = bias[col];
#pragma unroll
          for (int r = 0; r < 4; r++)
            ((bf16_t*)Cout)[hmi(row_b + r, col)] = (bf16_t)((acc[m][n][r] + bia) * QSCALE);
        } else if (col < 2048) {
          const float bia = biasB[col - 1024];
#pragma unroll
          for (int r = 0; r < 4; r++)
            ((bf16_t*)Cout + 4194304)[hmi(row_b + r, col - 1024)] =
                (bf16_t)(acc[m][n][r] + bia);
        } else {
          const int vcol = col - 2048;
          const float bia = biasC[vcol];
          bf16x4 vv;
#pragma unroll
          for (int r = 0; r < 4; r++) vv[r] = (bf16_t)(acc[m][n][r] + bia);
          const int bb2 = row_b >> 11, tt = row_b & 2047;
          *(bf16x4*)&aux[(((long)(bb2 << 4) + (vcol >> 6)) * 64 + (vcol & 63)) * 2048 + tt] = vv;
        }
      }
    }
}

// ---------------- GEMM BK=64 (Wo: BN=64, 48KB LDS): EPI 1 = bias+res -> fp32 ----------------
template <int EPI, int BN>
__global__ __launch_bounds__(256) void gemm64(const bf16_t* __restrict__ A,
                                              const bf16_t* __restrict__ Bt,
                                              const float* __restrict__ bias,
                                              const float* __restrict__ res,
                                              void* __restrict__ Cout,
                                              int M, int N, int K) {
  constexpr int NF = BN / 32;
  constexpr int NBI = BN / 32;
  __shared__ bf16_t a_lds[2][128 * 64];
  __shared__ bf16_t b_lds[2][BN * 64];
  const int tid = threadIdx.x, l = tid & 63, w = tid >> 6;
  const int wr = w >> 1, wc = w & 1;
  const int nwg = gridDim.x * gridDim.y;
  const int orig = blockIdx.y * gridDim.x + blockIdx.x;
  const int lid = (orig & 7) * (nwg >> 3) + (orig >> 3);
  const int bx = lid % gridDim.x, by = lid / gridDim.x;
  const int m0 = by * 128, n0 = bx * BN;
  const int lr = l & 15, lg = l >> 4;
  long a_src[4];
  int ldst[4];
#pragma unroll
  for (int i = 0; i < 4; i++) {
    const int row = i * 32 + w * 8 + (l >> 3);
    const int sc = ((l & 7) ^ (row & 7)) * 8;
    a_src[i] = (long)(m0 + row) * K + sc;
    ldst[i] = (i * 32 + w * 8) * 64;
  }
  long b_src[NBI];
#pragma unroll
  for (int i = 0; i < NBI; i++) {
    const int row = i * 32 + w * 8 + (l >> 3);
    const int sc = ((l & 7) ^ (row & 7)) * 8;
    b_src[i] = (long)(n0 + row) * K + sc;
  }
  const int nk = K >> 6;
  f32x4 acc[4][NF] = {};
#pragma unroll
  for (int i = 0; i < 4; i++) gload16(A + a_src[i], &a_lds[0][ldst[i]]);
#pragma unroll
  for (int i = 0; i < NBI; i++) gload16(Bt + b_src[i], &b_lds[0][ldst[i]]);
  __syncthreads();
  const int sw = (lr & 7) << 4;
  int cur = 0;
  for (int t = 0; t < nk; t++) {
    if (t + 1 < nk) {
      const long k0 = (long)(t + 1) * 64;
#pragma unroll
      for (int i = 0; i < 4; i++) gload16(A + a_src[i] + k0, &a_lds[cur ^ 1][ldst[i]]);
#pragma unroll
      for (int i = 0; i < NBI; i++) gload16(Bt + b_src[i] + k0, &b_lds[cur ^ 1][ldst[i]]);
    }
    const char* ab = (const char*)&a_lds[cur][0];
    const char* bb = (const char*)&b_lds[cur][0];
    bf16x8 af[4][2], bfr[NF][2];
#pragma unroll
    for (int m = 0; m < 4; m++) {
      const int rb = (wr * 64 + m * 16 + lr) * 128;
      af[m][0] = *(const bf16x8*)(ab + rb + ((16 * lg) ^ sw));
      af[m][1] = *(const bf16x8*)(ab + rb + ((16 * lg + 64) ^ sw));
    }
#pragma unroll
    for (int n = 0; n < NF; n++) {
      const int rb = (wc * (BN / 2) + n * 16 + lr) * 128;
      bfr[n][0] = *(const bf16x8*)(bb + rb + ((16 * lg) ^ sw));
      bfr[n][1] = *(const bf16x8*)(bb + rb + ((16 * lg + 64) ^ sw));
    }
    __builtin_amdgcn_s_setprio(1);
#pragma unroll
    for (int kk = 0; kk < 2; kk++)
#pragma unroll
      for (int m = 0; m < 4; m++)
#pragma unroll
        for (int n = 0; n < NF; n++)
          acc[m][n] = mfma16(af[m][kk], bfr[n][kk], acc[m][n]);
    __builtin_amdgcn_s_setprio(0);
    __syncthreads();
    cur ^= 1;
  }
#pragma unroll
  for (int m = 0; m < 4; m++)
#pragma unroll
    for (int n = 0; n < NF; n++) {
      const int row_b = m0 + wr * 64 + m * 16 + (l >> 4) * 4;
      const int col = n0 + wc * (BN / 2) + n * 16 + lr;
      const float bia = bias[col];
#pragma unroll
      for (int r = 0; r < 4; r++) {
        const long idx = (long)(row_b + r) * N + col;
        ((float*)Cout)[idx] = acc[m][n][r] + bia + res[idx];
      }
    }
}

// -------- fused attention v10: 8 waves, 3-buffer K/V, counted vmcnt (T4 on attn) --------
// Replaces per-tile __syncthreads() (vmcnt(0) drain) with vmcnt(2)+raw barrier: tile
// t+1's 2 loads stay in flight across the barrier. V staged unconditionally so the
// per-tile load count is uniform (vmcnt arithmetic requires it); masked tiles still
// skip P-pack/PV compute. Buffer (t+2)%3 reuse is WAR-safe: last read in iter t-1,
// drained by the top-of-iter-t barrier (same invariant as the verified gemm32).
__global__ __launch_bounds__(512) void attn_kernel(const bf16_t* __restrict__ qhm,
                                                   const bf16_t* __restrict__ khm,
                                                   const bf16_t* __restrict__ vtg,
                                                   bf16_t* __restrict__ og,
                                                   const int* __restrict__ maskp) {
  const int T = 2048, HP = 1024;
  __shared__ bf16_t k_lds[3][64 * 64];
  __shared__ bf16_t vt_lds[3][64 * 64];
  __shared__ bf16_t p_lds[8 * 16 * 72];
  const int bh = blockIdx.x, b = bh >> 4, h = bh & 15;
  const int q0 = blockIdx.y * 128;
  const int tid = threadIdx.x, l = tid & 63, w = tid >> 6;  // w in [0,8)
  const int lr = l & 15, lg = l >> 4, lg4 = lg * 4;
  const int srow = q0 + w * 16 + lr;
  const bf16_t* kbase = khm + (long)bh * T * 64;
  const bf16_t* vbase = vtg + (long)bh * 64 * T;
  const bf16_t* qr = qhm + ((long)bh * 2048 + srow) * 64 + lg * 8;
  bf16x8 qf0 = *(const bf16x8*)qr;
  bf16x8 qf1 = *(const bf16x8*)(qr + 32);
  bf16_t* pl = &p_lds[w * 16 * 72];
  float lpart = 0.0f;
  f32x4 oat[4] = {};

  const int swz = (lr & 7) << 4;
  const int fo0 = lr * 128 + ((16 * lg) ^ swz);
  const int fo1 = lr * 128 + ((64 + 16 * lg) ^ swz);

  const bool do_mask = (maskp[0] != 0);
  const int nM = do_mask ? (q0 >> 6) : 0;
  const int nt = T >> 6;

  const int srow8 = l >> 3, sch = l & 7;
  const int ssc = (sch ^ srow8) * 8;
  const int srw = w * 8 + srow8;
  // prologue: stage tiles 0 and 1 (K then V per tile; 2 loads/tile/thread)
  gload16(kbase + (long)srw * 64 + ssc, &k_lds[0][w * 512]);
  gload16(vbase + (long)srw * 2048 + 0 + ssc, &vt_lds[0][w * 512]);
  gload16(kbase + (long)(64 + srw) * 64 + ssc, &k_lds[1][w * 512]);
  gload16(vbase + (long)srw * 2048 + 64 + ssc, &vt_lds[1][w * 512]);

  int cu = 0;
  for (int t = 0; t < nt; t++) {
    const int t0 = t << 6;
    const int mode = (t < nM) ? 0 : ((do_mask && t < nM + 2) ? 1 : 2);
    // counted wait: tile t's 2 loads complete; tile t+1's 2 stay in flight
    if (t + 1 < nt) asm volatile("s_waitcnt vmcnt(2)" ::: "memory");
    else            asm volatile("s_waitcnt vmcnt(0)" ::: "memory");
    __builtin_amdgcn_s_barrier();
    __builtin_amdgcn_sched_barrier(0);
    if (t + 2 < nt) {
      const int t2 = (t + 2) << 6;
      const int nb = cu >= 1 ? cu - 1 : 2;  // (cu+2)%3
      gload16(kbase + (long)(t2 + srw) * 64 + ssc, &k_lds[nb][w * 512]);
      gload16(vbase + (long)srw * 2048 + t2 + ssc, &vt_lds[nb][w * 512]);
    }
    const char* kb = (const char*)&k_lds[cu][0];
    f32x4 sacc[4];
    __builtin_amdgcn_s_setprio(1);
#pragma unroll
    for (int n = 0; n < 4; n++) {
      bf16x8 kf0 = *(const bf16x8*)(kb + n * 2048 + fo0);
      bf16x8 kf1 = *(const bf16x8*)(kb + n * 2048 + fo1);
      f32x4 z = {0.0f, 0.0f, 0.0f, 0.0f};
      z = mfma16(kf0, qf0, z);
      sacc[n] = mfma16(kf1, qf1, z);
    }
    __builtin_amdgcn_s_setprio(0);
    float pv[4][4], psn[4];
#pragma unroll
    for (int n = 0; n < 4; n++) {
      pv[n][0] = exp2_fast(sacc[n][0]);
      pv[n][1] = exp2_fast(sacc[n][1]);
      pv[n][2] = exp2_fast(sacc[n][2]);
      pv[n][3] = exp2_fast(sacc[n][3]);
      psn[n] = (pv[n][0] + pv[n][1]) + (pv[n][2] + pv[n][3]);
    }
    lpart += (psn[0] + psn[1]) + (psn[2] + psn[3]);
    if (mode > 0) {
#pragma unroll
      for (int n = 0; n < 4; n++) {
        bf16x4 pk;
#pragma unroll
        for (int r = 0; r < 4; r++) {
          float v = pv[n][r];
          if (mode == 1 && (t0 + n * 16 + lg4 + r) <= srow) v = 0.0f;
          pk[r] = (bf16_t)v;
        }
        *(bf16x4*)&pl[lr * 72 + n * 16 + lg4] = pk;
      }
      const char* vtb = (const char*)&vt_lds[cu][0];
      __builtin_amdgcn_s_setprio(1);
#pragma unroll
      for (int kk = 0; kk < 2; kk++) {
        bf16x8 pb = *(bf16x8*)&pl[lr * 72 + kk * 32 + lg * 8];
        const int fkk = lr * 128 + ((kk * 64 + 16 * lg) ^ swz);
#pragma unroll
        for (int np = 0; np < 4; np++) {
          bf16x8 vtf = *(const bf16x8*)(vtb + np * 2048 + fkk);
          oat[np] = mfma16(vtf, pb, oat[np]);
        }
      }
      __builtin_amdgcn_s_setprio(0);
    }
    cu = cu < 2 ? cu + 1 : 0;
  }
  float lsum = lpart;
  lsum += __shfl_xor(lsum, 16);
  lsum += __shfl_xor(lsum, 32);
  const float inv = 1.0f / lsum;
#pragma unroll
  for (int np = 0; np < 4; np++) {
    bf16x4 o4;
#pragma unroll
    for (int r = 0; r < 4; r++) o4[r] = (bf16_t)(oat[np][r] * inv);
    *(bf16x4*)&pl[lr * 72 + np * 16 + lg4] = o4;
  }
  const int es = l >> 2, ec = (l & 3) * 16;
  bf16x8 o0 = *(bf16x8*)&pl[es * 72 + ec];
  bf16x8 o1 = *(bf16x8*)&pl[es * 72 + ec + 8];
  bf16_t* orow = og + (long)(b * 2048 + q0 + w * 16 + es) * HP + h * 64 + ec;
  *(bf16x8*)&orow[0] = o0;
  *(bf16x8*)&orow[8] = o1;
}

extern "C" void kernel_launch(void* const* d_in, const int* in_sizes, int n_in,
                              void* d_out, int out_size, void* d_ws, size_t ws_size,
                              hipStream_t stream) {
  const float* x = (const float*)d_in[0];
  const float* y = (const float*)d_in[1];
  const float* gxg = (const float*)d_in[2];
  const float* gxb = (const float*)d_in[3];
  const float* gyg = (const float*)d_in[4];
  const float* gyb = (const float*)d_in[5];
  const float* Wq = (const float*)d_in[6];
  const float* bq = (const float*)d_in[7];
  const float* Wk = (const float*)d_in[8];
  const float* bk = (const float*)d_in[9];
  const float* Wv = (const float*)d_in[10];
  const float* bv = (const float*)d_in[11];
  const float* Wo = (const float*)d_in[12];
  const float* bo = (const float*)d_in[13];
  const float* gdg = (const float*)d_in[14];
  const float* gdb = (const float*)d_in[15];
  const float* W1 = (const float*)d_in[16];
  const float* b1 = (const float*)d_in[17];
  const float* W2 = (const float*)d_in[18];
  const float* b2 = (const float*)d_in[19];
  const int* maskp = (const int*)d_in[20];
  float* out = (float*)d_out;

  char* ws = (char*)d_ws;
  const long MB = 1024 * 1024;
  bf16_t* xn = (bf16_t*)(ws + 0);
  bf16_t* yn = (bf16_t*)(ws + 8 * MB);
  bf16_t* WqkvT = (bf16_t*)(ws + 16 * MB);
  bf16_t* WoT = (bf16_t*)(ws + 22 * MB);
  bf16_t* W1T = (bf16_t*)(ws + 24 * MB);
  bf16_t* W2T = (bf16_t*)(ws + 32 * MB);
  bf16_t* qhm = (bf16_t*)(ws + 40 * MB);
  bf16_t* vTb = (bf16_t*)(ws + 64 * MB);
  bf16_t* ob = (bf16_t*)(ws + 0);
  bf16_t* xd = (bf16_t*)(ws + 8 * MB);
  bf16_t* hb = (bf16_t*)(ws + 40 * MB);
  bf16_t* w2part = (bf16_t*)(ws + 0);  // [4][4096][1024] bf16 = 32MB; xn/ob/xd dead by W2
  bf16_t* khm = qhm + 4194304;

  prep_all<<<11264, 256, 0, stream>>>(Wq, Wk, Wv, Wo, W1, W2, WqkvT, WoT, W1T, W2T, x, y, gxg,
                                      gxb, gyg, gyb, xn, yn);
  gemm32<5, 128, 12><<<dim3(24, 32), 256, 0, stream>>>(xn, yn, WqkvT, bq, bk, bv, vTb, qhm,
                                                       4096, 3072, 1024);
  attn_kernel<<<dim3(32, 16), 512, 0, stream>>>(qhm, khm, vTb, ob, maskp);
  gemm64<1, 64><<<dim3(16, 32), 256, 0, stream>>>(ob, WoT, bo, x, out, 4096, 1024, 1024);
  ln_kernel<<<4096, 256, 0, stream>>>(out, gdg, gdb, xd);
  gemm256<2, 4><<<dim3(16, 16), 512, 0, stream>>>(xd, W1T, b1, hb, 4096, 4096, 1024);
  gemm256<7, 4><<<dim3(4, 16, 4), 512, 0, stream>>>(hb, W2T, nullptr, w2part, 4096, 1024, 4096);
  reduce_w2<<<4096, 256, 0, stream>>>(w2part, b2, out);
}